// Round 15
// baseline (324.960 us; speedup 1.0000x reference)
//
#include <hip/hip_runtime.h>
#include <hip/hip_bf16.h>

#define NND 50000
#define NCATS 3
#define VOC 1000
#define EDIM 16
#define NNUMF 16
#define FMAP 32
#define FIN 128          // 3*16 + 16 + 64
#define HID 64
#define NH 4
#define EB 400000
#define ETOT 450000      // EB + NND self loops
#define M1 256
#define M2 128
#define EPS_BN 1e-5f
#define NB 196           // ceil(NND/256)
#define YSTR 264         // LDS y-tile row stride in shorts (bank-spread)

typedef __attribute__((ext_vector_type(8))) short bf16x8;
typedef __attribute__((ext_vector_type(4))) float f32x4;

__device__ __forceinline__ float lrelu(float x) { return x > 0.f ? x : 0.2f * x; }

__device__ __forceinline__ unsigned short bfu(float f) {
    unsigned u = __float_as_uint(f);
    unsigned r = (u + 0x7FFFu + ((u >> 16) & 1u)) >> 16;
    return (unsigned short)r;
}
__device__ __forceinline__ float bf2f(unsigned short h) {
    return __uint_as_float((unsigned)h << 16);
}

// ================= CSR build (once; graph identical for both layers) =================
__global__ void k_zero_deg(int* __restrict__ deg) {
    int i = blockIdx.x * blockDim.x + threadIdx.x;
    if (i < NND) deg[i] = 0;
}

__global__ void k_count(const int* __restrict__ ei, int* __restrict__ deg) {
    int e = blockIdx.x * blockDim.x + threadIdx.x;
    if (e >= ETOT) return;
    int d = (e < EB) ? ei[EB + e] : e - EB;
    atomicAdd(&deg[d], 1);
}

__global__ __launch_bounds__(256) void k_bsum(const int* __restrict__ deg,
                                              int* __restrict__ bsum) {
    int i = blockIdx.x * 256 + threadIdx.x;
    int v = (i < NND) ? deg[i] : 0;
    #pragma unroll
    for (int ofs = 32; ofs; ofs >>= 1) v += __shfl_xor(v, ofs, 64);
    __shared__ int ws[4];
    if ((threadIdx.x & 63) == 0) ws[threadIdx.x >> 6] = v;
    __syncthreads();
    if (threadIdx.x == 0) bsum[blockIdx.x] = ws[0] + ws[1] + ws[2] + ws[3];
}

__global__ __launch_bounds__(256) void k_bscan(const int* __restrict__ bsum,
                                               int* __restrict__ bpre,
                                               int* __restrict__ off) {
    __shared__ int sh[256];
    const int t = threadIdx.x;
    int v = (t < NB) ? bsum[t] : 0;
    sh[t] = v;
    __syncthreads();
    for (int ofs = 1; ofs < 256; ofs <<= 1) {
        int u = (t >= ofs) ? sh[t - ofs] : 0;
        __syncthreads();
        sh[t] += u;
        __syncthreads();
    }
    if (t < NB) bpre[t] = sh[t] - v;
    if (t == 0) off[NND] = ETOT;
}

__global__ __launch_bounds__(256) void k_offsets(const int* __restrict__ deg,
                                                 const int* __restrict__ bpre,
                                                 int* __restrict__ off,
                                                 int* __restrict__ cur) {
    __shared__ int sh[256];
    const int t = threadIdx.x;
    const int i = blockIdx.x * 256 + t;
    int v = (i < NND) ? deg[i] : 0;
    sh[t] = v;
    __syncthreads();
    for (int ofs = 1; ofs < 256; ofs <<= 1) {
        int u = (t >= ofs) ? sh[t - ofs] : 0;
        __syncthreads();
        sh[t] += u;
        __syncthreads();
    }
    int excl = sh[t] - v + bpre[blockIdx.x];
    if (i < NND) { off[i] = excl; cur[i] = excl; }
}

__global__ void k_fill(const int* __restrict__ ei, int* __restrict__ cur,
                       int* __restrict__ srcs) {
    int e = blockIdx.x * blockDim.x + threadIdx.x;
    if (e >= ETOT) return;
    int s, d;
    if (e < EB) { s = ei[e]; d = ei[EB + e]; } else { s = d = e - EB; }
    int p = atomicAdd(&cur[d], 1);
    srcs[p] = s;
}

// ===== pack W1/W2 (bf16), Ws (stacked gatW, hi+lo), pW (proj, hi+lo) into MFMA B-frag order =====
__global__ __launch_bounds__(256) void k_packw(
    const float* __restrict__ W1, const float* __restrict__ W2,
    const float* __restrict__ gatW, const float* __restrict__ pW,
    unsigned short* __restrict__ W1f, unsigned short* __restrict__ W2f,
    unsigned short* __restrict__ Wsf, unsigned short* __restrict__ Wsl,
    unsigned short* __restrict__ pWh, unsigned short* __restrict__ pWl)
{
    int i = blockIdx.x * 256 + threadIdx.x;
    if (i < 16384) {
        int j = i & 7, l = (i >> 3) & 63, t = i >> 9;
        int kc = t & 1, cb = t >> 1;
        int k = kc * 32 + ((l >> 4) * 8) + j, c = cb * 16 + (l & 15);
        W1f[i] = bfu(W1[k * 256 + c]);
    }
    if (i < 32768) {
        int j = i & 7, l = (i >> 3) & 63, t = i >> 9;
        int kc = t & 7, cb = t >> 3;
        int k = kc * 32 + ((l >> 4) * 8) + j, c = cb * 16 + (l & 15);
        W2f[i] = bfu(W2[k * 128 + c]);
    }
    if (i < 32768) {   // Ws: 2 layers x (4 cb x 8 kc); Ws[r][c] = W[r&63][(r>>6)*64+c]
        int j = i & 7, l = (i >> 3) & 63, t = (i >> 9) & 31, lay = i >> 14;
        int kc = t & 7, cb = t >> 3;
        int r = kc * 32 + ((l >> 4) * 8) + j, c = cb * 16 + (l & 15);
        float w = gatW[lay * 16384 + (r & 63) * 256 + (r >> 6) * 64 + c];
        unsigned short h = bfu(w);
        Wsf[i] = h;
        Wsl[i] = bfu(w - bf2f(h));
    }
    if (i < 8192) {    // pW: 4 cb x 4 kc; pW[k][c], k<128, c<64
        int j = i & 7, l = (i >> 3) & 63, t = i >> 9;
        int kc = t & 3, cb = t >> 2;
        int k = kc * 32 + ((l >> 4) * 8) + j, c = cb * 16 + (l & 15);
        float w = pW[k * 64 + c];
        unsigned short h = bfu(w);
        pWh[i] = h;
        pWl[i] = bfu(w - bf2f(h));
    }
}

// ====== K1: featurize + MFMA project (128 -> 64), split bf16, 64-node tiles ======
// writes fp32 x AND bf16 shadow xbf
__global__ __launch_bounds__(256) void k_feat_mfma(
    const int* __restrict__ x_cat, const float* __restrict__ x_num,
    const float* __restrict__ x_coord, const float* __restrict__ emb,
    const float* __restrict__ fB,
    const unsigned short* __restrict__ pWh, const unsigned short* __restrict__ pWl,
    const float* __restrict__ pb, float* __restrict__ xout,
    unsigned short* __restrict__ xbf)
{
    __shared__ __align__(16) unsigned short fh[64 * 128];  // 16 KB
    __shared__ __align__(16) unsigned short fl[64 * 128];  // 16 KB
    const int tid = threadIdx.x;
    const int lane = tid & 63, wid = tid >> 6;
    const int cl = lane & 15, lg = lane >> 4;
    const int nw = wid * 16;
    bf16x8 wfh[4][4], wfl[4][4];
    #pragma unroll
    for (int cb = 0; cb < 4; ++cb)
        #pragma unroll
        for (int kc = 0; kc < 4; ++kc) {
            wfh[cb][kc] = *(const bf16x8*)&pWh[(((cb << 2) + kc) * 64 + lane) * 8];
            wfl[cb][kc] = *(const bf16x8*)&pWl[(((cb << 2) + kc) * 64 + lane) * 8];
        }
    float pbr[4];
    #pragma unroll
    for (int cb = 0; cb < 4; ++cb) pbr[cb] = pb[cb * 16 + cl];
    const int ntiles = (NND + 63) / 64;   // 782
    for (int t = blockIdx.x; t < ntiles; t += gridDim.x) {
        const int n0 = t * 64;
        __syncthreads();
        for (int r = 0; r < 16; ++r) {
            const int row = nw + r;
            const int n = n0 + row;
            float v = 0.f, v2 = 0.f;
            if (n < NND) {
                if (lane < 48) {
                    int c = lane >> 4, j = lane & 15;
                    int idx = x_cat[n * NCATS + c];
                    v = emb[((size_t)c * VOC + idx) * EDIM + j];
                } else {
                    v = x_num[n * NNUMF + (lane - 48)];
                }
                float c0 = x_coord[n * 2 + 0], c1 = x_coord[n * 2 + 1];
                int f = lane & 31;
                float xp = 6.283185307179586f * (c0 * fB[f] + c1 * fB[FMAP + f]);
                v2 = (lane < 32) ? sinf(xp) : cosf(xp);
            }
            unsigned short h = bfu(v);
            fh[row * 128 + lane] = h;
            fl[row * 128 + lane] = bfu(v - bf2f(h));
            unsigned short h2 = bfu(v2);
            fh[row * 128 + 64 + lane] = h2;
            fl[row * 128 + 64 + lane] = bfu(v2 - bf2f(h2));
        }
        __syncthreads();
        bf16x8 afh[4], afl[4];
        #pragma unroll
        for (int kc = 0; kc < 4; ++kc) {
            afh[kc] = *(const bf16x8*)&fh[(nw + cl) * 128 + kc * 32 + lg * 8];
            afl[kc] = *(const bf16x8*)&fl[(nw + cl) * 128 + kc * 32 + lg * 8];
        }
        #pragma unroll
        for (int cb = 0; cb < 4; ++cb) {
            float bv = pbr[cb];
            f32x4 a = {bv, bv, bv, bv};
            #pragma unroll
            for (int kc = 0; kc < 4; ++kc)
                a = __builtin_amdgcn_mfma_f32_16x16x32_bf16(afl[kc], wfh[cb][kc], a, 0, 0, 0);
            #pragma unroll
            for (int kc = 0; kc < 4; ++kc)
                a = __builtin_amdgcn_mfma_f32_16x16x32_bf16(afh[kc], wfl[cb][kc], a, 0, 0, 0);
            #pragma unroll
            for (int kc = 0; kc < 4; ++kc)
                a = __builtin_amdgcn_mfma_f32_16x16x32_bf16(afh[kc], wfh[cb][kc], a, 0, 0, 0);
            #pragma unroll
            for (int r = 0; r < 4; ++r) {
                int n = n0 + nw + lg * 4 + r;
                if (n < NND) {
                    xout[(size_t)n * HID + cb * 16 + cl] = a[r];
                    xbf[(size_t)n * HID + cb * 16 + cl] = bfu(a[r]);
                }
            }
        }
    }
}

// ====== K2a: va for BOTH layers upfront (depends only on weights) ======
__global__ __launch_bounds__(512) void k_va2(
    const float* __restrict__ gatW, const float* __restrict__ attS,
    const float* __restrict__ attD, float* __restrict__ va2)
{
    const int lay = blockIdx.x;
    const float* W = gatW + (size_t)lay * 16384;
    const int t = threadIdx.x;
    const int k = t >> 3, q = t & 7, hh = q & 3;
    const float* a = ((q >= 4) ? attD : attS) + lay * NH * HID;
    float s = 0.f;
    #pragma unroll 8
    for (int d = 0; d < HID; ++d)
        s += W[k * 256 + hh * 64 + d] * a[hh * 64 + d];
    va2[lay * 512 + k * 8 + q] = s;
}

// ================= K2b: alphas from xbf (+ zero bnst in block 0) =================
__global__ __launch_bounds__(256) void k_alpha2(
    const unsigned short* __restrict__ xbf, const float* __restrict__ va,
    float* __restrict__ alphS, float* __restrict__ alphD, float* __restrict__ bnst)
{
    __shared__ float vas[64 * 8];
    const int tid = threadIdx.x;
    if (blockIdx.x == 0) bnst[tid] = 0.f;
    for (int i = tid; i < 512; i += 256) vas[i] = va[i];
    __syncthreads();
    const int lane = tid & 63, wid = tid >> 6;
    const float4 vS = *(const float4*)&vas[lane * 8];
    const float4 vD = *(const float4*)&vas[lane * 8 + 4];
    for (int n = blockIdx.x * 4 + wid; n < NND; n += gridDim.x * 4) {
        float v = bf2f(xbf[(size_t)n * HID + lane]);
        float s0 = v * vS.x, s1 = v * vS.y, s2 = v * vS.z, s3 = v * vS.w;
        float d0 = v * vD.x, d1 = v * vD.y, d2 = v * vD.z, d3 = v * vD.w;
        #pragma unroll
        for (int ofs = 32; ofs; ofs >>= 1) {
            s0 += __shfl_xor(s0, ofs, 64); s1 += __shfl_xor(s1, ofs, 64);
            s2 += __shfl_xor(s2, ofs, 64); s3 += __shfl_xor(s3, ofs, 64);
            d0 += __shfl_xor(d0, ofs, 64); d1 += __shfl_xor(d1, ofs, 64);
            d2 += __shfl_xor(d2, ofs, 64); d3 += __shfl_xor(d3, ofs, 64);
        }
        if (lane == 0) {
            *(float4*)(alphS + (size_t)n * 4) = make_float4(s0, s1, s2, s3);
            *(float4*)(alphD + (size_t)n * 4) = make_float4(d0, d1, d2, d3);
        }
    }
}

// ====== K3: FUSED single-pass aggregate (bf16 x gathers, y -> LDS) + MFMA transform ======
__global__ __launch_bounds__(256) void k_agg_trans(
    const int* __restrict__ off, const int* __restrict__ srcs,
    const float* __restrict__ alphS, const float* __restrict__ alphD,
    const unsigned short* __restrict__ xbf,
    const unsigned short* __restrict__ Wh, const unsigned short* __restrict__ Wl_,
    const float* __restrict__ gat_b, float* __restrict__ accum,
    float* __restrict__ bnst)
{
    __shared__ __align__(16) unsigned short ylh[16 * YSTR];  // 8.25 KB
    __shared__ __align__(16) unsigned short yll[16 * YSTR];  // 8.25 KB
    __shared__ float sred[2][4][16];
    const int tid = threadIdx.x;
    const int l16 = tid & 15, gi = tid >> 4;      // aggregation role: group gi, lane l16
    const int lane = tid & 63, wid = tid >> 6;    // transform role: cb = wid
    const int cl = lane & 15, lg = lane >> 4;
    const float bd = gat_b[wid * 16 + cl];
    float s1 = 0.f, s2 = 0.f;
    const int ngrp = NND / 16;   // 3125
    for (int g = blockIdx.x; g < ngrp; g += gridDim.x) {
        const int d = g * 16 + gi;               // always < NND
        // ---------- single-pass aggregation ----------
        const int o0 = off[d];
        const int deg = off[d + 1] - o0;
        const float4 ad = *(const float4*)(alphD + (size_t)d * 4);
        float dn0 = 0.f, dn1 = 0.f, dn2 = 0.f, dn3 = 0.f;
        float ya[4][4];
        #pragma unroll
        for (int h = 0; h < 4; ++h)
            #pragma unroll
            for (int c = 0; c < 4; ++c) ya[h][c] = 0.f;
        for (int c0 = 0; c0 < deg; c0 += 16) {
            const int m = min(16, deg - c0);
            int sE = 0; float w0 = 0.f, w1 = 0.f, w2 = 0.f, w3 = 0.f;
            if (l16 < m) {
                sE = srcs[o0 + c0 + l16];
                float4 as = *(const float4*)(alphS + (size_t)sE * 4);
                w0 = __expf(lrelu(as.x + ad.x));
                w1 = __expf(lrelu(as.y + ad.y));
                w2 = __expf(lrelu(as.z + ad.z));
                w3 = __expf(lrelu(as.w + ad.w));
            }
            dn0 += w0; dn1 += w1; dn2 += w2; dn3 += w3;
            int j = 0;
            for (; j + 2 <= m; j += 2) {
                const int sj0 = __shfl(sE, j + 0, 16);
                const int sj1 = __shfl(sE, j + 1, 16);
                const ushort4 xu0 = *(const ushort4*)(xbf + (size_t)sj0 * HID + l16 * 4);
                const ushort4 xu1 = *(const ushort4*)(xbf + (size_t)sj1 * HID + l16 * 4);
                float a0 = __shfl(w0, j, 16), a1 = __shfl(w1, j, 16);
                float a2 = __shfl(w2, j, 16), a3 = __shfl(w3, j, 16);
                float x0 = bf2f(xu0.x), x1 = bf2f(xu0.y), x2 = bf2f(xu0.z), x3 = bf2f(xu0.w);
                ya[0][0] = fmaf(a0, x0, ya[0][0]); ya[0][1] = fmaf(a0, x1, ya[0][1]);
                ya[0][2] = fmaf(a0, x2, ya[0][2]); ya[0][3] = fmaf(a0, x3, ya[0][3]);
                ya[1][0] = fmaf(a1, x0, ya[1][0]); ya[1][1] = fmaf(a1, x1, ya[1][1]);
                ya[1][2] = fmaf(a1, x2, ya[1][2]); ya[1][3] = fmaf(a1, x3, ya[1][3]);
                ya[2][0] = fmaf(a2, x0, ya[2][0]); ya[2][1] = fmaf(a2, x1, ya[2][1]);
                ya[2][2] = fmaf(a2, x2, ya[2][2]); ya[2][3] = fmaf(a2, x3, ya[2][3]);
                ya[3][0] = fmaf(a3, x0, ya[3][0]); ya[3][1] = fmaf(a3, x1, ya[3][1]);
                ya[3][2] = fmaf(a3, x2, ya[3][2]); ya[3][3] = fmaf(a3, x3, ya[3][3]);
                a0 = __shfl(w0, j + 1, 16); a1 = __shfl(w1, j + 1, 16);
                a2 = __shfl(w2, j + 1, 16); a3 = __shfl(w3, j + 1, 16);
                x0 = bf2f(xu1.x); x1 = bf2f(xu1.y); x2 = bf2f(xu1.z); x3 = bf2f(xu1.w);
                ya[0][0] = fmaf(a0, x0, ya[0][0]); ya[0][1] = fmaf(a0, x1, ya[0][1]);
                ya[0][2] = fmaf(a0, x2, ya[0][2]); ya[0][3] = fmaf(a0, x3, ya[0][3]);
                ya[1][0] = fmaf(a1, x0, ya[1][0]); ya[1][1] = fmaf(a1, x1, ya[1][1]);
                ya[1][2] = fmaf(a1, x2, ya[1][2]); ya[1][3] = fmaf(a1, x3, ya[1][3]);
                ya[2][0] = fmaf(a2, x0, ya[2][0]); ya[2][1] = fmaf(a2, x1, ya[2][1]);
                ya[2][2] = fmaf(a2, x2, ya[2][2]); ya[2][3] = fmaf(a2, x3, ya[2][3]);
                ya[3][0] = fmaf(a3, x0, ya[3][0]); ya[3][1] = fmaf(a3, x1, ya[3][1]);
                ya[3][2] = fmaf(a3, x2, ya[3][2]); ya[3][3] = fmaf(a3, x3, ya[3][3]);
            }
            if (j < m) {
                const int sj0 = __shfl(sE, j, 16);
                const ushort4 xu0 = *(const ushort4*)(xbf + (size_t)sj0 * HID + l16 * 4);
                float a0 = __shfl(w0, j, 16), a1 = __shfl(w1, j, 16);
                float a2 = __shfl(w2, j, 16), a3 = __shfl(w3, j, 16);
                float x0 = bf2f(xu0.x), x1 = bf2f(xu0.y), x2 = bf2f(xu0.z), x3 = bf2f(xu0.w);
                ya[0][0] = fmaf(a0, x0, ya[0][0]); ya[0][1] = fmaf(a0, x1, ya[0][1]);
                ya[0][2] = fmaf(a0, x2, ya[0][2]); ya[0][3] = fmaf(a0, x3, ya[0][3]);
                ya[1][0] = fmaf(a1, x0, ya[1][0]); ya[1][1] = fmaf(a1, x1, ya[1][1]);
                ya[1][2] = fmaf(a1, x2, ya[1][2]); ya[1][3] = fmaf(a1, x3, ya[1][3]);
                ya[2][0] = fmaf(a2, x0, ya[2][0]); ya[2][1] = fmaf(a2, x1, ya[2][1]);
                ya[2][2] = fmaf(a2, x2, ya[2][2]); ya[2][3] = fmaf(a2, x3, ya[2][3]);
                ya[3][0] = fmaf(a3, x0, ya[3][0]); ya[3][1] = fmaf(a3, x1, ya[3][1]);
                ya[3][2] = fmaf(a3, x2, ya[3][2]); ya[3][3] = fmaf(a3, x3, ya[3][3]);
            }
        }
        #pragma unroll
        for (int ofs = 8; ofs; ofs >>= 1) {
            dn0 += __shfl_xor(dn0, ofs, 64); dn1 += __shfl_xor(dn1, ofs, 64);
            dn2 += __shfl_xor(dn2, ofs, 64); dn3 += __shfl_xor(dn3, ofs, 64);
        }
        {
            const float invh[4] = {
                __fdividef(1.f, dn0 + 1e-16f), __fdividef(1.f, dn1 + 1e-16f),
                __fdividef(1.f, dn2 + 1e-16f), __fdividef(1.f, dn3 + 1e-16f)};
            #pragma unroll
            for (int h = 0; h < 4; ++h) {
                ushort4 uh, ul;
                float v0 = ya[h][0] * invh[h]; uh.x = bfu(v0); ul.x = bfu(v0 - bf2f(uh.x));
                float v1 = ya[h][1] * invh[h]; uh.y = bfu(v1); ul.y = bfu(v1 - bf2f(uh.y));
                float v2 = ya[h][2] * invh[h]; uh.z = bfu(v2); ul.z = bfu(v2 - bf2f(uh.z));
                float v3 = ya[h][3] * invh[h]; uh.w = bfu(v3); ul.w = bfu(v3 - bf2f(uh.w));
                *(ushort4*)&ylh[gi * YSTR + h * 64 + l16 * 4] = uh;
                *(ushort4*)&yll[gi * YSTR + h * 64 + l16 * 4] = ul;
            }
        }
        __syncthreads();
        // ---------- transform phase (split bf16, 3 independent chains) ----------
        {
            bf16x8 afh[8], afl[8], wfh[8], wfl[8];
            #pragma unroll
            for (int kc = 0; kc < 8; ++kc) {
                afh[kc] = *(const bf16x8*)&ylh[cl * YSTR + kc * 32 + lg * 8];
                afl[kc] = *(const bf16x8*)&yll[cl * YSTR + kc * 32 + lg * 8];
                wfh[kc] = *(const bf16x8*)&Wh[(size_t)(((wid << 3) + kc) * 64 + lane) * 8];
                wfl[kc] = *(const bf16x8*)&Wl_[(size_t)(((wid << 3) + kc) * 64 + lane) * 8];
            }
            f32x4 a0 = {0.f, 0.f, 0.f, 0.f};
            f32x4 a1 = {0.f, 0.f, 0.f, 0.f};
            f32x4 a2 = {0.f, 0.f, 0.f, 0.f};
            #pragma unroll
            for (int kc = 0; kc < 8; ++kc) {
                a0 = __builtin_amdgcn_mfma_f32_16x16x32_bf16(afl[kc], wfh[kc], a0, 0, 0, 0);
                a1 = __builtin_amdgcn_mfma_f32_16x16x32_bf16(afh[kc], wfl[kc], a1, 0, 0, 0);
                a2 = __builtin_amdgcn_mfma_f32_16x16x32_bf16(afh[kc], wfh[kc], a2, 0, 0, 0);
            }
            const int n0 = g * 16;
            #pragma unroll
            for (int r = 0; r < 4; ++r) {
                float gv = (a0[r] + a1[r] + a2[r]) * 0.25f + bd;
                accum[(size_t)(n0 + lg * 4 + r) * HID + wid * 16 + cl] = gv;
                s1 += gv; s2 += gv * gv;
            }
        }
        __syncthreads();   // protect LDS before next group's writes
    }
    // ---------- BN-stats epilogue ----------
    s1 += __shfl_xor(s1, 16, 64); s2 += __shfl_xor(s2, 16, 64);
    s1 += __shfl_xor(s1, 32, 64); s2 += __shfl_xor(s2, 32, 64);
    if (lane < 16) { sred[0][wid][cl] = s1; sred[1][wid][cl] = s2; }
    __syncthreads();
    if (tid < 64) {
        atomicAdd(&bnst[tid], sred[0][tid >> 4][tid & 15]);
        atomicAdd(&bnst[128 + tid], sred[1][tid >> 4][tid & 15]);
    }
}

// ========= K5: BN apply + relu + residual (in place on x, + bf16 shadow) =========
__global__ void k_bn_apply(const float* __restrict__ accum, const float* __restrict__ bnst,
                           const float* __restrict__ gamma, const float* __restrict__ beta,
                           float* __restrict__ x, unsigned short* __restrict__ xbf)
{
    int i = blockIdx.x * blockDim.x + threadIdx.x;   // float4 index
    if (i >= NND * 16) return;
    int dg = (i & 15) * 4;
    float4 a = ((const float4*)accum)[i];
    float4 xv = ((float4*)x)[i];
    float r[4]; float av[4] = {a.x, a.y, a.z, a.w}; float xx[4] = {xv.x, xv.y, xv.z, xv.w};
    #pragma unroll
    for (int c = 0; c < 4; ++c) {
        int d = dg + c;
        float mu = bnst[d] * (1.f / NND);
        float var = bnst[128 + d] * (1.f / NND) - mu * mu;
        float inv = rsqrtf(var + EPS_BN);
        float yv = (av[c] - mu) * inv * gamma[d] + beta[d];
        r[c] = fmaxf(yv, 0.f) + xx[c];
    }
    ((float4*)x)[i] = make_float4(r[0], r[1], r[2], r[3]);
    ushort4 u;
    u.x = bfu(r[0]); u.y = bfu(r[1]); u.z = bfu(r[2]); u.w = bfu(r[3]);
    *(ushort4*)(xbf + (size_t)i * 4) = u;
}

// ====== K6: fused MFMA MLP (stages x tile from bf16 shadow) ======
__global__ __launch_bounds__(256, 1) void k_mlp_mfma(
    const unsigned short* __restrict__ xbf,
    const unsigned short* __restrict__ W1f, const unsigned short* __restrict__ W2f,
    const float* __restrict__ b1, const float* __restrict__ b2,
    const float* __restrict__ W3, const float* __restrict__ b3,
    float* __restrict__ out)
{
    __shared__ __align__(16) unsigned short W1s[16384];  // 32 KB (frag order)
    __shared__ __align__(16) unsigned short W2s[32768];  // 64 KB (frag order)
    __shared__ __align__(16) unsigned short xs[64 * 64]; // 8 KB
    __shared__ __align__(16) unsigned short z1s[64 * 256]; // 32 KB
    __shared__ float b1s[256], b2s[128], w3s[128];
    const int tid = threadIdx.x;
    const int lane = tid & 63, wid = tid >> 6;
    {
        const uint4* s1 = (const uint4*)W1f; uint4* d1 = (uint4*)W1s;
        for (int i = tid; i < 2048; i += 256) d1[i] = s1[i];
        const uint4* s2 = (const uint4*)W2f; uint4* d2 = (uint4*)W2s;
        for (int i = tid; i < 4096; i += 256) d2[i] = s2[i];
        if (tid < 256) b1s[tid] = b1[tid];
        if (tid < 128) { b2s[tid] = b2[tid]; w3s[tid] = W3[tid]; }
    }
    const float bb3 = b3[0];
    const int nw = wid * 16;
    const int cl = lane & 15, lg = lane >> 4;
    const int ntiles = (NND + 63) / 64;
    for (int t = blockIdx.x; t < ntiles; t += gridDim.x) {
        const int n0 = t * 64;
        __syncthreads();
        #pragma unroll
        for (int q = 0; q < 2; ++q) {
            int i = q * 256 + tid;            // 0..511, 16 B each
            int row = i >> 3, k8 = (i & 7) * 8;
            int n = n0 + row;
            uint4 v = (n < NND) ? *(const uint4*)(xbf + (size_t)n * HID + k8)
                                : make_uint4(0u, 0u, 0u, 0u);
            *(uint4*)&xs[row * 64 + k8] = v;
        }
        __syncthreads();
        #pragma unroll 4
        for (int cb = 0; cb < 16; ++cb) {
            float bv = b1s[cb * 16 + cl];
            f32x4 a = {bv, bv, bv, bv};
            #pragma unroll
            for (int kc = 0; kc < 2; ++kc) {
                bf16x8 af = *(const bf16x8*)&xs[(nw + cl) * 64 + kc * 32 + lg * 8];
                bf16x8 bf = *(const bf16x8*)&W1s[(((cb << 1) + kc) * 64 + lane) * 8];
                a = __builtin_amdgcn_mfma_f32_16x16x32_bf16(af, bf, a, 0, 0, 0);
            }
            #pragma unroll
            for (int r = 0; r < 4; ++r)
                z1s[(nw + lg * 4 + r) * 256 + cb * 16 + cl] = bfu(fmaxf(a[r], 0.f));
        }
        __syncthreads();
        bf16x8 af2[8];
        #pragma unroll
        for (int kc = 0; kc < 8; ++kc)
            af2[kc] = *(const bf16x8*)&z1s[(nw + cl) * 256 + kc * 32 + lg * 8];
        float p0 = 0.f, p1 = 0.f, p2 = 0.f, p3 = 0.f;
        #pragma unroll
        for (int cb = 0; cb < 8; ++cb) {
            float bv = b2s[cb * 16 + cl];
            f32x4 a = {bv, bv, bv, bv};
            #pragma unroll
            for (int kc = 0; kc < 8; ++kc) {
                bf16x8 bf = *(const bf16x8*)&W2s[(((cb << 3) + kc) * 64 + lane) * 8];
                a = __builtin_amdgcn_mfma_f32_16x16x32_bf16(af2[kc], bf, a, 0, 0, 0);
            }
            float w3v = w3s[cb * 16 + cl];
            p0 = fmaf(fmaxf(a[0], 0.f), w3v, p0);
            p1 = fmaf(fmaxf(a[1], 0.f), w3v, p1);
            p2 = fmaf(fmaxf(a[2], 0.f), w3v, p2);
            p3 = fmaf(fmaxf(a[3], 0.f), w3v, p3);
        }
        #pragma unroll
        for (int ofs = 1; ofs <= 8; ofs <<= 1) {
            p0 += __shfl_xor(p0, ofs, 64); p1 += __shfl_xor(p1, ofs, 64);
            p2 += __shfl_xor(p2, ofs, 64); p3 += __shfl_xor(p3, ofs, 64);
        }
        if (cl == 0) {
            int base = n0 + nw + lg * 4;
            if (base + 0 < NND) out[base + 0] = p0 + bb3;
            if (base + 1 < NND) out[base + 1] = p1 + bb3;
            if (base + 2 < NND) out[base + 2] = p2 + bb3;
            if (base + 3 < NND) out[base + 3] = p3 + bb3;
        }
    }
}

extern "C" void kernel_launch(void* const* d_in, const int* in_sizes, int n_in,
                              void* d_out, int out_size, void* d_ws, size_t ws_size,
                              hipStream_t stream) {
    const int*   x_cat   = (const int*)  d_in[0];
    const float* x_num   = (const float*)d_in[1];
    const float* x_coord = (const float*)d_in[2];
    const int*   eidx    = (const int*)  d_in[3];
    const float* emb     = (const float*)d_in[4];
    const float* fB      = (const float*)d_in[5];
    const float* pW      = (const float*)d_in[6];
    const float* pb      = (const float*)d_in[7];
    const float* gatW    = (const float*)d_in[8];
    const float* attS    = (const float*)d_in[9];
    const float* attD    = (const float*)d_in[10];
    const float* gatB    = (const float*)d_in[11];
    const float* bnG     = (const float*)d_in[12];
    const float* bnB     = (const float*)d_in[13];
    const float* W1      = (const float*)d_in[14];
    const float* b1      = (const float*)d_in[15];
    const float* W2      = (const float*)d_in[16];
    const float* b2      = (const float*)d_in[17];
    const float* W3      = (const float*)d_in[18];
    const float* b3      = (const float*)d_in[19];
    float* out = (float*)d_out;

    char* p = (char*)d_ws;
    float* x     = (float*)p;  p += (size_t)NND * HID * 4;
    unsigned short* xbf = (unsigned short*)p; p += (size_t)NND * HID * 2;
    float* alphS = (float*)p;  p += (size_t)NND * NH * 4;
    float* alphD = (float*)p;  p += (size_t)NND * NH * 4;
    float* accum = (float*)p;  p += (size_t)NND * HID * 4;
    float* bnst  = (float*)p;  p += 1024;
    float* va2   = (float*)p;  p += 1024 * 4;
    unsigned short* W1f = (unsigned short*)p; p += 16384 * 2;
    unsigned short* W2f = (unsigned short*)p; p += 32768 * 2;
    unsigned short* Wsf = (unsigned short*)p; p += 32768 * 2;
    unsigned short* Wsl = (unsigned short*)p; p += 32768 * 2;
    unsigned short* pWh = (unsigned short*)p; p += 8192 * 2;
    unsigned short* pWl = (unsigned short*)p; p += 8192 * 2;
    int*   deg   = (int*)p;    p += (size_t)NND * 4;
    int*   cur   = (int*)p;    p += (size_t)NND * 4;
    int*   off   = (int*)p;    p += (size_t)(NND + 1) * 4 + 4;
    int*   srcs  = (int*)p;    p += (size_t)ETOT * 4;
    int*   bsum  = (int*)p;    p += NB * 4;
    int*   bpre  = (int*)p;    p += NB * 4;

    // CSR build (graph constant across layers) + weight packing + va (both layers)
    k_zero_deg<<<NB, 256, 0, stream>>>(deg);
    k_count<<<(ETOT + 255) / 256, 256, 0, stream>>>(eidx, deg);
    k_bsum<<<NB, 256, 0, stream>>>(deg, bsum);
    k_bscan<<<1, 256, 0, stream>>>(bsum, bpre, off);
    k_offsets<<<NB, 256, 0, stream>>>(deg, bpre, off, cur);
    k_fill<<<(ETOT + 255) / 256, 256, 0, stream>>>(eidx, cur, srcs);
    k_packw<<<192, 256, 0, stream>>>(W1, W2, gatW, pW, W1f, W2f, Wsf, Wsl, pWh, pWl);
    k_va2<<<2, 512, 0, stream>>>(gatW, attS, attD, va2);

    k_feat_mfma<<<512, 256, 0, stream>>>(x_cat, x_num, x_coord, emb, fB, pWh, pWl, pb,
                                         x, xbf);
    for (int l = 0; l < 2; ++l) {
        k_alpha2<<<2048, 256, 0, stream>>>(xbf, va2 + (size_t)l * 512, alphS, alphD, bnst);
        k_agg_trans<<<2048, 256, 0, stream>>>(off, srcs, alphS, alphD, xbf,
                                              Wsf + (size_t)l * 16384,
                                              Wsl + (size_t)l * 16384,
                                              gatB + l * HID, accum, bnst);
        k_bn_apply<<<3125, 256, 0, stream>>>(accum, bnst, bnG + l * HID, bnB + l * HID,
                                             x, xbf);
    }
    k_mlp_mfma<<<256, 256, 0, stream>>>(xbf, W1f, W2f, b1, b2, W3, b3, out);
}

// Round 16
// 302.633 us; speedup vs baseline: 1.0738x; 1.0738x over previous
//
#include <hip/hip_runtime.h>
#include <hip/hip_bf16.h>

#define NND 50000
#define NCATS 3
#define VOC 1000
#define EDIM 16
#define NNUMF 16
#define FMAP 32
#define FIN 128          // 3*16 + 16 + 64
#define HID 64
#define NH 4
#define EB 400000
#define ETOT 450000      // EB + NND self loops
#define M1 256
#define M2 128
#define EPS_BN 1e-5f
#define NB 196           // ceil(NND/256)
#define YSTR 264         // LDS y-tile row stride in shorts (bank-spread)

typedef __attribute__((ext_vector_type(8))) short bf16x8;
typedef __attribute__((ext_vector_type(4))) float f32x4;

__device__ __forceinline__ float lrelu(float x) { return x > 0.f ? x : 0.2f * x; }

__device__ __forceinline__ unsigned short bfu(float f) {
    unsigned u = __float_as_uint(f);
    unsigned r = (u + 0x7FFFu + ((u >> 16) & 1u)) >> 16;
    return (unsigned short)r;
}
__device__ __forceinline__ float bf2f(unsigned short h) {
    return __uint_as_float((unsigned)h << 16);
}

// ================= CSR build (once; graph identical for both layers) =================
__global__ void k_zero_deg(int* __restrict__ deg) {
    int i = blockIdx.x * blockDim.x + threadIdx.x;
    if (i < NND) deg[i] = 0;
}

__global__ void k_count(const int* __restrict__ ei, int* __restrict__ deg) {
    int e = blockIdx.x * blockDim.x + threadIdx.x;
    if (e >= ETOT) return;
    int d = (e < EB) ? ei[EB + e] : e - EB;
    atomicAdd(&deg[d], 1);
}

__global__ __launch_bounds__(256) void k_bsum(const int* __restrict__ deg,
                                              int* __restrict__ bsum) {
    int i = blockIdx.x * 256 + threadIdx.x;
    int v = (i < NND) ? deg[i] : 0;
    #pragma unroll
    for (int ofs = 32; ofs; ofs >>= 1) v += __shfl_xor(v, ofs, 64);
    __shared__ int ws[4];
    if ((threadIdx.x & 63) == 0) ws[threadIdx.x >> 6] = v;
    __syncthreads();
    if (threadIdx.x == 0) bsum[blockIdx.x] = ws[0] + ws[1] + ws[2] + ws[3];
}

__global__ __launch_bounds__(256) void k_bscan(const int* __restrict__ bsum,
                                               int* __restrict__ bpre,
                                               int* __restrict__ off) {
    __shared__ int sh[256];
    const int t = threadIdx.x;
    int v = (t < NB) ? bsum[t] : 0;
    sh[t] = v;
    __syncthreads();
    for (int ofs = 1; ofs < 256; ofs <<= 1) {
        int u = (t >= ofs) ? sh[t - ofs] : 0;
        __syncthreads();
        sh[t] += u;
        __syncthreads();
    }
    if (t < NB) bpre[t] = sh[t] - v;
    if (t == 0) off[NND] = ETOT;
}

__global__ __launch_bounds__(256) void k_offsets(const int* __restrict__ deg,
                                                 const int* __restrict__ bpre,
                                                 int* __restrict__ off,
                                                 int* __restrict__ cur) {
    __shared__ int sh[256];
    const int t = threadIdx.x;
    const int i = blockIdx.x * 256 + t;
    int v = (i < NND) ? deg[i] : 0;
    sh[t] = v;
    __syncthreads();
    for (int ofs = 1; ofs < 256; ofs <<= 1) {
        int u = (t >= ofs) ? sh[t - ofs] : 0;
        __syncthreads();
        sh[t] += u;
        __syncthreads();
    }
    int excl = sh[t] - v + bpre[blockIdx.x];
    if (i < NND) { off[i] = excl; cur[i] = excl; }
}

__global__ void k_fill(const int* __restrict__ ei, int* __restrict__ cur,
                       int* __restrict__ srcs) {
    int e = blockIdx.x * blockDim.x + threadIdx.x;
    if (e >= ETOT) return;
    int s, d;
    if (e < EB) { s = ei[e]; d = ei[EB + e]; } else { s = d = e - EB; }
    int p = atomicAdd(&cur[d], 1);
    srcs[p] = s;
}

// ===== pack W1/W2 (bf16), Ws (stacked gatW, hi+lo), pW (proj, hi+lo) into MFMA B-frag order =====
__global__ __launch_bounds__(256) void k_packw(
    const float* __restrict__ W1, const float* __restrict__ W2,
    const float* __restrict__ gatW, const float* __restrict__ pW,
    unsigned short* __restrict__ W1f, unsigned short* __restrict__ W2f,
    unsigned short* __restrict__ Wsf, unsigned short* __restrict__ Wsl,
    unsigned short* __restrict__ pWh, unsigned short* __restrict__ pWl)
{
    int i = blockIdx.x * 256 + threadIdx.x;
    if (i < 16384) {
        int j = i & 7, l = (i >> 3) & 63, t = i >> 9;
        int kc = t & 1, cb = t >> 1;
        int k = kc * 32 + ((l >> 4) * 8) + j, c = cb * 16 + (l & 15);
        W1f[i] = bfu(W1[k * 256 + c]);
    }
    if (i < 32768) {
        int j = i & 7, l = (i >> 3) & 63, t = i >> 9;
        int kc = t & 7, cb = t >> 3;
        int k = kc * 32 + ((l >> 4) * 8) + j, c = cb * 16 + (l & 15);
        W2f[i] = bfu(W2[k * 128 + c]);
    }
    if (i < 32768) {   // Ws: 2 layers x (4 cb x 8 kc); Ws[r][c] = W[r&63][(r>>6)*64+c]
        int j = i & 7, l = (i >> 3) & 63, t = (i >> 9) & 31, lay = i >> 14;
        int kc = t & 7, cb = t >> 3;
        int r = kc * 32 + ((l >> 4) * 8) + j, c = cb * 16 + (l & 15);
        float w = gatW[lay * 16384 + (r & 63) * 256 + (r >> 6) * 64 + c];
        unsigned short h = bfu(w);
        Wsf[i] = h;
        Wsl[i] = bfu(w - bf2f(h));
    }
    if (i < 8192) {    // pW: 4 cb x 4 kc; pW[k][c], k<128, c<64
        int j = i & 7, l = (i >> 3) & 63, t = i >> 9;
        int kc = t & 3, cb = t >> 2;
        int k = kc * 32 + ((l >> 4) * 8) + j, c = cb * 16 + (l & 15);
        float w = pW[k * 64 + c];
        unsigned short h = bfu(w);
        pWh[i] = h;
        pWl[i] = bfu(w - bf2f(h));
    }
}

// ====== K1: featurize + MFMA project (128 -> 64), split bf16, 64-node tiles ======
// writes fp32 x AND bf16 shadow xbf
__global__ __launch_bounds__(256) void k_feat_mfma(
    const int* __restrict__ x_cat, const float* __restrict__ x_num,
    const float* __restrict__ x_coord, const float* __restrict__ emb,
    const float* __restrict__ fB,
    const unsigned short* __restrict__ pWh, const unsigned short* __restrict__ pWl,
    const float* __restrict__ pb, float* __restrict__ xout,
    unsigned short* __restrict__ xbf)
{
    __shared__ __align__(16) unsigned short fh[64 * 128];  // 16 KB
    __shared__ __align__(16) unsigned short fl[64 * 128];  // 16 KB
    const int tid = threadIdx.x;
    const int lane = tid & 63, wid = tid >> 6;
    const int cl = lane & 15, lg = lane >> 4;
    const int nw = wid * 16;
    bf16x8 wfh[4][4], wfl[4][4];
    #pragma unroll
    for (int cb = 0; cb < 4; ++cb)
        #pragma unroll
        for (int kc = 0; kc < 4; ++kc) {
            wfh[cb][kc] = *(const bf16x8*)&pWh[(((cb << 2) + kc) * 64 + lane) * 8];
            wfl[cb][kc] = *(const bf16x8*)&pWl[(((cb << 2) + kc) * 64 + lane) * 8];
        }
    float pbr[4];
    #pragma unroll
    for (int cb = 0; cb < 4; ++cb) pbr[cb] = pb[cb * 16 + cl];
    const int ntiles = (NND + 63) / 64;   // 782
    for (int t = blockIdx.x; t < ntiles; t += gridDim.x) {
        const int n0 = t * 64;
        __syncthreads();
        for (int r = 0; r < 16; ++r) {
            const int row = nw + r;
            const int n = n0 + row;
            float v = 0.f, v2 = 0.f;
            if (n < NND) {
                if (lane < 48) {
                    int c = lane >> 4, j = lane & 15;
                    int idx = x_cat[n * NCATS + c];
                    v = emb[((size_t)c * VOC + idx) * EDIM + j];
                } else {
                    v = x_num[n * NNUMF + (lane - 48)];
                }
                float c0 = x_coord[n * 2 + 0], c1 = x_coord[n * 2 + 1];
                int f = lane & 31;
                float xp = 6.283185307179586f * (c0 * fB[f] + c1 * fB[FMAP + f]);
                v2 = (lane < 32) ? sinf(xp) : cosf(xp);
            }
            unsigned short h = bfu(v);
            fh[row * 128 + lane] = h;
            fl[row * 128 + lane] = bfu(v - bf2f(h));
            unsigned short h2 = bfu(v2);
            fh[row * 128 + 64 + lane] = h2;
            fl[row * 128 + 64 + lane] = bfu(v2 - bf2f(h2));
        }
        __syncthreads();
        bf16x8 afh[4], afl[4];
        #pragma unroll
        for (int kc = 0; kc < 4; ++kc) {
            afh[kc] = *(const bf16x8*)&fh[(nw + cl) * 128 + kc * 32 + lg * 8];
            afl[kc] = *(const bf16x8*)&fl[(nw + cl) * 128 + kc * 32 + lg * 8];
        }
        #pragma unroll
        for (int cb = 0; cb < 4; ++cb) {
            float bv = pbr[cb];
            f32x4 a = {bv, bv, bv, bv};
            #pragma unroll
            for (int kc = 0; kc < 4; ++kc)
                a = __builtin_amdgcn_mfma_f32_16x16x32_bf16(afl[kc], wfh[cb][kc], a, 0, 0, 0);
            #pragma unroll
            for (int kc = 0; kc < 4; ++kc)
                a = __builtin_amdgcn_mfma_f32_16x16x32_bf16(afh[kc], wfl[cb][kc], a, 0, 0, 0);
            #pragma unroll
            for (int kc = 0; kc < 4; ++kc)
                a = __builtin_amdgcn_mfma_f32_16x16x32_bf16(afh[kc], wfh[cb][kc], a, 0, 0, 0);
            #pragma unroll
            for (int r = 0; r < 4; ++r) {
                int n = n0 + nw + lg * 4 + r;
                if (n < NND) {
                    xout[(size_t)n * HID + cb * 16 + cl] = a[r];
                    xbf[(size_t)n * HID + cb * 16 + cl] = bfu(a[r]);
                }
            }
        }
    }
}

// ====== K2a: va for BOTH layers upfront (depends only on weights) ======
__global__ __launch_bounds__(512) void k_va2(
    const float* __restrict__ gatW, const float* __restrict__ attS,
    const float* __restrict__ attD, float* __restrict__ va2)
{
    const int lay = blockIdx.x;
    const float* W = gatW + (size_t)lay * 16384;
    const int t = threadIdx.x;
    const int k = t >> 3, q = t & 7, hh = q & 3;
    const float* a = ((q >= 4) ? attD : attS) + lay * NH * HID;
    float s = 0.f;
    #pragma unroll 8
    for (int d = 0; d < HID; ++d)
        s += W[k * 256 + hh * 64 + d] * a[hh * 64 + d];
    va2[lay * 512 + k * 8 + q] = s;
}

// ================= K2b: alphas from xbf (+ zero bnst in block 0) =================
__global__ __launch_bounds__(256) void k_alpha2(
    const unsigned short* __restrict__ xbf, const float* __restrict__ va,
    float* __restrict__ alphS, float* __restrict__ alphD, float* __restrict__ bnst)
{
    __shared__ float vas[64 * 8];
    const int tid = threadIdx.x;
    if (blockIdx.x == 0) bnst[tid] = 0.f;
    for (int i = tid; i < 512; i += 256) vas[i] = va[i];
    __syncthreads();
    const int lane = tid & 63, wid = tid >> 6;
    const float4 vS = *(const float4*)&vas[lane * 8];
    const float4 vD = *(const float4*)&vas[lane * 8 + 4];
    for (int n = blockIdx.x * 4 + wid; n < NND; n += gridDim.x * 4) {
        float v = bf2f(xbf[(size_t)n * HID + lane]);
        float s0 = v * vS.x, s1 = v * vS.y, s2 = v * vS.z, s3 = v * vS.w;
        float d0 = v * vD.x, d1 = v * vD.y, d2 = v * vD.z, d3 = v * vD.w;
        #pragma unroll
        for (int ofs = 32; ofs; ofs >>= 1) {
            s0 += __shfl_xor(s0, ofs, 64); s1 += __shfl_xor(s1, ofs, 64);
            s2 += __shfl_xor(s2, ofs, 64); s3 += __shfl_xor(s3, ofs, 64);
            d0 += __shfl_xor(d0, ofs, 64); d1 += __shfl_xor(d1, ofs, 64);
            d2 += __shfl_xor(d2, ofs, 64); d3 += __shfl_xor(d3, ofs, 64);
        }
        if (lane == 0) {
            *(float4*)(alphS + (size_t)n * 4) = make_float4(s0, s1, s2, s3);
            *(float4*)(alphD + (size_t)n * 4) = make_float4(d0, d1, d2, d3);
        }
    }
}

// ====== K3: FUSED single-pass aggregate (bf16 x gathers, y -> LDS) + MFMA transform ======
__global__ __launch_bounds__(256) void k_agg_trans(
    const int* __restrict__ off, const int* __restrict__ srcs,
    const float* __restrict__ alphS, const float* __restrict__ alphD,
    const unsigned short* __restrict__ xbf,
    const unsigned short* __restrict__ Wh, const unsigned short* __restrict__ Wl_,
    const float* __restrict__ gat_b, float* __restrict__ accum,
    float* __restrict__ bnst)
{
    __shared__ __align__(16) unsigned short ylh[16 * YSTR];  // 8.25 KB
    __shared__ __align__(16) unsigned short yll[16 * YSTR];  // 8.25 KB
    __shared__ float sred[2][4][16];
    const int tid = threadIdx.x;
    const int l16 = tid & 15, gi = tid >> 4;      // aggregation role: group gi, lane l16
    const int lane = tid & 63, wid = tid >> 6;    // transform role: cb = wid
    const int cl = lane & 15, lg = lane >> 4;
    const float bd = gat_b[wid * 16 + cl];
    float s1 = 0.f, s2 = 0.f;
    const int ngrp = NND / 16;   // 3125
    for (int g = blockIdx.x; g < ngrp; g += gridDim.x) {
        const int d = g * 16 + gi;               // always < NND
        // ---------- single-pass aggregation ----------
        const int o0 = off[d];
        const int deg = off[d + 1] - o0;
        const float4 ad = *(const float4*)(alphD + (size_t)d * 4);
        float dn0 = 0.f, dn1 = 0.f, dn2 = 0.f, dn3 = 0.f;
        float ya[4][4];
        #pragma unroll
        for (int h = 0; h < 4; ++h)
            #pragma unroll
            for (int c = 0; c < 4; ++c) ya[h][c] = 0.f;
        for (int c0 = 0; c0 < deg; c0 += 16) {
            const int m = min(16, deg - c0);
            int sE = 0; float w0 = 0.f, w1 = 0.f, w2 = 0.f, w3 = 0.f;
            if (l16 < m) {
                sE = srcs[o0 + c0 + l16];
                float4 as = *(const float4*)(alphS + (size_t)sE * 4);
                w0 = __expf(lrelu(as.x + ad.x));
                w1 = __expf(lrelu(as.y + ad.y));
                w2 = __expf(lrelu(as.z + ad.z));
                w3 = __expf(lrelu(as.w + ad.w));
            }
            dn0 += w0; dn1 += w1; dn2 += w2; dn3 += w3;
            int j = 0;
            for (; j + 2 <= m; j += 2) {
                const int sj0 = __shfl(sE, j + 0, 16);
                const int sj1 = __shfl(sE, j + 1, 16);
                const ushort4 xu0 = *(const ushort4*)(xbf + (size_t)sj0 * HID + l16 * 4);
                const ushort4 xu1 = *(const ushort4*)(xbf + (size_t)sj1 * HID + l16 * 4);
                float a0 = __shfl(w0, j, 16), a1 = __shfl(w1, j, 16);
                float a2 = __shfl(w2, j, 16), a3 = __shfl(w3, j, 16);
                float x0 = bf2f(xu0.x), x1 = bf2f(xu0.y), x2 = bf2f(xu0.z), x3 = bf2f(xu0.w);
                ya[0][0] = fmaf(a0, x0, ya[0][0]); ya[0][1] = fmaf(a0, x1, ya[0][1]);
                ya[0][2] = fmaf(a0, x2, ya[0][2]); ya[0][3] = fmaf(a0, x3, ya[0][3]);
                ya[1][0] = fmaf(a1, x0, ya[1][0]); ya[1][1] = fmaf(a1, x1, ya[1][1]);
                ya[1][2] = fmaf(a1, x2, ya[1][2]); ya[1][3] = fmaf(a1, x3, ya[1][3]);
                ya[2][0] = fmaf(a2, x0, ya[2][0]); ya[2][1] = fmaf(a2, x1, ya[2][1]);
                ya[2][2] = fmaf(a2, x2, ya[2][2]); ya[2][3] = fmaf(a2, x3, ya[2][3]);
                ya[3][0] = fmaf(a3, x0, ya[3][0]); ya[3][1] = fmaf(a3, x1, ya[3][1]);
                ya[3][2] = fmaf(a3, x2, ya[3][2]); ya[3][3] = fmaf(a3, x3, ya[3][3]);
                a0 = __shfl(w0, j + 1, 16); a1 = __shfl(w1, j + 1, 16);
                a2 = __shfl(w2, j + 1, 16); a3 = __shfl(w3, j + 1, 16);
                x0 = bf2f(xu1.x); x1 = bf2f(xu1.y); x2 = bf2f(xu1.z); x3 = bf2f(xu1.w);
                ya[0][0] = fmaf(a0, x0, ya[0][0]); ya[0][1] = fmaf(a0, x1, ya[0][1]);
                ya[0][2] = fmaf(a0, x2, ya[0][2]); ya[0][3] = fmaf(a0, x3, ya[0][3]);
                ya[1][0] = fmaf(a1, x0, ya[1][0]); ya[1][1] = fmaf(a1, x1, ya[1][1]);
                ya[1][2] = fmaf(a1, x2, ya[1][2]); ya[1][3] = fmaf(a1, x3, ya[1][3]);
                ya[2][0] = fmaf(a2, x0, ya[2][0]); ya[2][1] = fmaf(a2, x1, ya[2][1]);
                ya[2][2] = fmaf(a2, x2, ya[2][2]); ya[2][3] = fmaf(a2, x3, ya[2][3]);
                ya[3][0] = fmaf(a3, x0, ya[3][0]); ya[3][1] = fmaf(a3, x1, ya[3][1]);
                ya[3][2] = fmaf(a3, x2, ya[3][2]); ya[3][3] = fmaf(a3, x3, ya[3][3]);
            }
            if (j < m) {
                const int sj0 = __shfl(sE, j, 16);
                const ushort4 xu0 = *(const ushort4*)(xbf + (size_t)sj0 * HID + l16 * 4);
                float a0 = __shfl(w0, j, 16), a1 = __shfl(w1, j, 16);
                float a2 = __shfl(w2, j, 16), a3 = __shfl(w3, j, 16);
                float x0 = bf2f(xu0.x), x1 = bf2f(xu0.y), x2 = bf2f(xu0.z), x3 = bf2f(xu0.w);
                ya[0][0] = fmaf(a0, x0, ya[0][0]); ya[0][1] = fmaf(a0, x1, ya[0][1]);
                ya[0][2] = fmaf(a0, x2, ya[0][2]); ya[0][3] = fmaf(a0, x3, ya[0][3]);
                ya[1][0] = fmaf(a1, x0, ya[1][0]); ya[1][1] = fmaf(a1, x1, ya[1][1]);
                ya[1][2] = fmaf(a1, x2, ya[1][2]); ya[1][3] = fmaf(a1, x3, ya[1][3]);
                ya[2][0] = fmaf(a2, x0, ya[2][0]); ya[2][1] = fmaf(a2, x1, ya[2][1]);
                ya[2][2] = fmaf(a2, x2, ya[2][2]); ya[2][3] = fmaf(a2, x3, ya[2][3]);
                ya[3][0] = fmaf(a3, x0, ya[3][0]); ya[3][1] = fmaf(a3, x1, ya[3][1]);
                ya[3][2] = fmaf(a3, x2, ya[3][2]); ya[3][3] = fmaf(a3, x3, ya[3][3]);
            }
        }
        #pragma unroll
        for (int ofs = 8; ofs; ofs >>= 1) {
            dn0 += __shfl_xor(dn0, ofs, 64); dn1 += __shfl_xor(dn1, ofs, 64);
            dn2 += __shfl_xor(dn2, ofs, 64); dn3 += __shfl_xor(dn3, ofs, 64);
        }
        {
            const float invh[4] = {
                __fdividef(1.f, dn0 + 1e-16f), __fdividef(1.f, dn1 + 1e-16f),
                __fdividef(1.f, dn2 + 1e-16f), __fdividef(1.f, dn3 + 1e-16f)};
            #pragma unroll
            for (int h = 0; h < 4; ++h) {
                ushort4 uh, ul;
                float v0 = ya[h][0] * invh[h]; uh.x = bfu(v0); ul.x = bfu(v0 - bf2f(uh.x));
                float v1 = ya[h][1] * invh[h]; uh.y = bfu(v1); ul.y = bfu(v1 - bf2f(uh.y));
                float v2 = ya[h][2] * invh[h]; uh.z = bfu(v2); ul.z = bfu(v2 - bf2f(uh.z));
                float v3 = ya[h][3] * invh[h]; uh.w = bfu(v3); ul.w = bfu(v3 - bf2f(uh.w));
                *(ushort4*)&ylh[gi * YSTR + h * 64 + l16 * 4] = uh;
                *(ushort4*)&yll[gi * YSTR + h * 64 + l16 * 4] = ul;
            }
        }
        __syncthreads();
        // ---------- transform phase (split bf16, 3 independent chains) ----------
        {
            bf16x8 afh[8], afl[8], wfh[8], wfl[8];
            #pragma unroll
            for (int kc = 0; kc < 8; ++kc) {
                afh[kc] = *(const bf16x8*)&ylh[cl * YSTR + kc * 32 + lg * 8];
                afl[kc] = *(const bf16x8*)&yll[cl * YSTR + kc * 32 + lg * 8];
                wfh[kc] = *(const bf16x8*)&Wh[(size_t)(((wid << 3) + kc) * 64 + lane) * 8];
                wfl[kc] = *(const bf16x8*)&Wl_[(size_t)(((wid << 3) + kc) * 64 + lane) * 8];
            }
            f32x4 a0 = {0.f, 0.f, 0.f, 0.f};
            f32x4 a1 = {0.f, 0.f, 0.f, 0.f};
            f32x4 a2 = {0.f, 0.f, 0.f, 0.f};
            #pragma unroll
            for (int kc = 0; kc < 8; ++kc) {
                a0 = __builtin_amdgcn_mfma_f32_16x16x32_bf16(afl[kc], wfh[kc], a0, 0, 0, 0);
                a1 = __builtin_amdgcn_mfma_f32_16x16x32_bf16(afh[kc], wfl[kc], a1, 0, 0, 0);
                a2 = __builtin_amdgcn_mfma_f32_16x16x32_bf16(afh[kc], wfh[kc], a2, 0, 0, 0);
            }
            const int n0 = g * 16;
            #pragma unroll
            for (int r = 0; r < 4; ++r) {
                float gv = (a0[r] + a1[r] + a2[r]) * 0.25f + bd;
                accum[(size_t)(n0 + lg * 4 + r) * HID + wid * 16 + cl] = gv;
                s1 += gv; s2 += gv * gv;
            }
        }
        __syncthreads();   // protect LDS before next group's writes
    }
    // ---------- BN-stats epilogue ----------
    s1 += __shfl_xor(s1, 16, 64); s2 += __shfl_xor(s2, 16, 64);
    s1 += __shfl_xor(s1, 32, 64); s2 += __shfl_xor(s2, 32, 64);
    if (lane < 16) { sred[0][wid][cl] = s1; sred[1][wid][cl] = s2; }
    __syncthreads();
    if (tid < 64) {
        atomicAdd(&bnst[tid], sred[0][tid >> 4][tid & 15]);
        atomicAdd(&bnst[128 + tid], sred[1][tid >> 4][tid & 15]);
    }
}

// ========= K5: BN apply + relu + residual (in place on x, + bf16 shadow) =========
__global__ void k_bn_apply(const float* __restrict__ accum, const float* __restrict__ bnst,
                           const float* __restrict__ gamma, const float* __restrict__ beta,
                           float* __restrict__ x, unsigned short* __restrict__ xbf)
{
    int i = blockIdx.x * blockDim.x + threadIdx.x;   // float4 index
    if (i >= NND * 16) return;
    int dg = (i & 15) * 4;
    float4 a = ((const float4*)accum)[i];
    float4 xv = ((float4*)x)[i];
    float r[4]; float av[4] = {a.x, a.y, a.z, a.w}; float xx[4] = {xv.x, xv.y, xv.z, xv.w};
    #pragma unroll
    for (int c = 0; c < 4; ++c) {
        int d = dg + c;
        float mu = bnst[d] * (1.f / NND);
        float var = bnst[128 + d] * (1.f / NND) - mu * mu;
        float inv = rsqrtf(var + EPS_BN);
        float yv = (av[c] - mu) * inv * gamma[d] + beta[d];
        r[c] = fmaxf(yv, 0.f) + xx[c];
    }
    ((float4*)x)[i] = make_float4(r[0], r[1], r[2], r[3]);
    ushort4 u;
    u.x = bfu(r[0]); u.y = bfu(r[1]); u.z = bfu(r[2]); u.w = bfu(r[3]);
    *(ushort4*)(xbf + (size_t)i * 4) = u;
}

// ====== K6: fused MFMA MLP (stages x tile from bf16 shadow) ======
__global__ __launch_bounds__(256, 1) void k_mlp_mfma(
    const unsigned short* __restrict__ xbf,
    const unsigned short* __restrict__ W1f, const unsigned short* __restrict__ W2f,
    const float* __restrict__ b1, const float* __restrict__ b2,
    const float* __restrict__ W3, const float* __restrict__ b3,
    float* __restrict__ out)
{
    __shared__ __align__(16) unsigned short W1s[16384];  // 32 KB (frag order)
    __shared__ __align__(16) unsigned short W2s[32768];  // 64 KB (frag order)
    __shared__ __align__(16) unsigned short xs[64 * 64]; // 8 KB
    __shared__ __align__(16) unsigned short z1s[64 * 256]; // 32 KB
    __shared__ float b1s[256], b2s[128], w3s[128];
    const int tid = threadIdx.x;
    const int lane = tid & 63, wid = tid >> 6;
    {
        const uint4* s1 = (const uint4*)W1f; uint4* d1 = (uint4*)W1s;
        for (int i = tid; i < 2048; i += 256) d1[i] = s1[i];
        const uint4* s2 = (const uint4*)W2f; uint4* d2 = (uint4*)W2s;
        for (int i = tid; i < 4096; i += 256) d2[i] = s2[i];
        if (tid < 256) b1s[tid] = b1[tid];
        if (tid < 128) { b2s[tid] = b2[tid]; w3s[tid] = W3[tid]; }
    }
    const float bb3 = b3[0];
    const int nw = wid * 16;
    const int cl = lane & 15, lg = lane >> 4;
    const int ntiles = (NND + 63) / 64;
    for (int t = blockIdx.x; t < ntiles; t += gridDim.x) {
        const int n0 = t * 64;
        __syncthreads();
        #pragma unroll
        for (int q = 0; q < 2; ++q) {
            int i = q * 256 + tid;            // 0..511, 16 B each
            int row = i >> 3, k8 = (i & 7) * 8;
            int n = n0 + row;
            uint4 v = (n < NND) ? *(const uint4*)(xbf + (size_t)n * HID + k8)
                                : make_uint4(0u, 0u, 0u, 0u);
            *(uint4*)&xs[row * 64 + k8] = v;
        }
        __syncthreads();
        #pragma unroll 4
        for (int cb = 0; cb < 16; ++cb) {
            float bv = b1s[cb * 16 + cl];
            f32x4 a = {bv, bv, bv, bv};
            #pragma unroll
            for (int kc = 0; kc < 2; ++kc) {
                bf16x8 af = *(const bf16x8*)&xs[(nw + cl) * 64 + kc * 32 + lg * 8];
                bf16x8 bf = *(const bf16x8*)&W1s[(((cb << 1) + kc) * 64 + lane) * 8];
                a = __builtin_amdgcn_mfma_f32_16x16x32_bf16(af, bf, a, 0, 0, 0);
            }
            #pragma unroll
            for (int r = 0; r < 4; ++r)
                z1s[(nw + lg * 4 + r) * 256 + cb * 16 + cl] = bfu(fmaxf(a[r], 0.f));
        }
        __syncthreads();
        bf16x8 af2[8];
        #pragma unroll
        for (int kc = 0; kc < 8; ++kc)
            af2[kc] = *(const bf16x8*)&z1s[(nw + cl) * 256 + kc * 32 + lg * 8];
        float p0 = 0.f, p1 = 0.f, p2 = 0.f, p3 = 0.f;
        #pragma unroll
        for (int cb = 0; cb < 8; ++cb) {
            float bv = b2s[cb * 16 + cl];
            f32x4 a = {bv, bv, bv, bv};
            #pragma unroll
            for (int kc = 0; kc < 8; ++kc) {
                bf16x8 bf = *(const bf16x8*)&W2s[(((cb << 3) + kc) * 64 + lane) * 8];
                a = __builtin_amdgcn_mfma_f32_16x16x32_bf16(af2[kc], bf, a, 0, 0, 0);
            }
            float w3v = w3s[cb * 16 + cl];
            p0 = fmaf(fmaxf(a[0], 0.f), w3v, p0);
            p1 = fmaf(fmaxf(a[1], 0.f), w3v, p1);
            p2 = fmaf(fmaxf(a[2], 0.f), w3v, p2);
            p3 = fmaf(fmaxf(a[3], 0.f), w3v, p3);
        }
        #pragma unroll
        for (int ofs = 1; ofs <= 8; ofs <<= 1) {
            p0 += __shfl_xor(p0, ofs, 64); p1 += __shfl_xor(p1, ofs, 64);
            p2 += __shfl_xor(p2, ofs, 64); p3 += __shfl_xor(p3, ofs, 64);
        }
        if (cl == 0) {
            int base = n0 + nw + lg * 4;
            if (base + 0 < NND) out[base + 0] = p0 + bb3;
            if (base + 1 < NND) out[base + 1] = p1 + bb3;
            if (base + 2 < NND) out[base + 2] = p2 + bb3;
            if (base + 3 < NND) out[base + 3] = p3 + bb3;
        }
    }
}

extern "C" void kernel_launch(void* const* d_in, const int* in_sizes, int n_in,
                              void* d_out, int out_size, void* d_ws, size_t ws_size,
                              hipStream_t stream) {
    const int*   x_cat   = (const int*)  d_in[0];
    const float* x_num   = (const float*)d_in[1];
    const float* x_coord = (const float*)d_in[2];
    const int*   eidx    = (const int*)  d_in[3];
    const float* emb     = (const float*)d_in[4];
    const float* fB      = (const float*)d_in[5];
    const float* pW      = (const float*)d_in[6];
    const float* pb      = (const float*)d_in[7];
    const float* gatW    = (const float*)d_in[8];
    const float* attS    = (const float*)d_in[9];
    const float* attD    = (const float*)d_in[10];
    const float* gatB    = (const float*)d_in[11];
    const float* bnG     = (const float*)d_in[12];
    const float* bnB     = (const float*)d_in[13];
    const float* W1      = (const float*)d_in[14];
    const float* b1      = (const float*)d_in[15];
    const float* W2      = (const float*)d_in[16];
    const float* b2      = (const float*)d_in[17];
    const float* W3      = (const float*)d_in[18];
    const float* b3      = (const float*)d_in[19];
    float* out = (float*)d_out;

    char* p = (char*)d_ws;
    float* x     = (float*)p;  p += (size_t)NND * HID * 4;
    unsigned short* xbf = (unsigned short*)p; p += (size_t)NND * HID * 2;
    float* alphS = (float*)p;  p += (size_t)NND * NH * 4;
    float* alphD = (float*)p;  p += (size_t)NND * NH * 4;
    float* accum = (float*)p;  p += (size_t)NND * HID * 4;
    float* bnst  = (float*)p;  p += 1024;
    float* va2   = (float*)p;  p += 1024 * 4;
    unsigned short* W1f = (unsigned short*)p; p += 16384 * 2;
    unsigned short* W2f = (unsigned short*)p; p += 32768 * 2;
    unsigned short* Wsf = (unsigned short*)p; p += 32768 * 2;
    unsigned short* Wsl = (unsigned short*)p; p += 32768 * 2;
    unsigned short* pWh = (unsigned short*)p; p += 8192 * 2;
    unsigned short* pWl = (unsigned short*)p; p += 8192 * 2;
    int*   deg   = (int*)p;    p += (size_t)NND * 4;
    int*   cur   = (int*)p;    p += (size_t)NND * 4;
    int*   off   = (int*)p;    p += (size_t)(NND + 1) * 4 + 4;
    int*   srcs  = (int*)p;    p += (size_t)ETOT * 4;
    int*   bsum  = (int*)p;    p += NB * 4;
    int*   bpre  = (int*)p;    p += NB * 4;

    // CSR build (graph constant across layers) + weight packing + va (both layers)
    k_zero_deg<<<NB, 256, 0, stream>>>(deg);
    k_count<<<(ETOT + 255) / 256, 256, 0, stream>>>(eidx, deg);
    k_bsum<<<NB, 256, 0, stream>>>(deg, bsum);
    k_bscan<<<1, 256, 0, stream>>>(bsum, bpre, off);
    k_offsets<<<NB, 256, 0, stream>>>(deg, bpre, off, cur);
    k_fill<<<(ETOT + 255) / 256, 256, 0, stream>>>(eidx, cur, srcs);
    k_packw<<<192, 256, 0, stream>>>(W1, W2, gatW, pW, W1f, W2f, Wsf, Wsl, pWh, pWl);
    k_va2<<<2, 512, 0, stream>>>(gatW, attS, attD, va2);

    k_feat_mfma<<<512, 256, 0, stream>>>(x_cat, x_num, x_coord, emb, fB, pWh, pWl, pb,
                                         x, xbf);
    for (int l = 0; l < 2; ++l) {
        k_alpha2<<<2048, 256, 0, stream>>>(xbf, va2 + (size_t)l * 512, alphS, alphD, bnst);
        k_agg_trans<<<1024, 256, 0, stream>>>(off, srcs, alphS, alphD, xbf,
                                              Wsf + (size_t)l * 16384,
                                              Wsl + (size_t)l * 16384,
                                              gatB + l * HID, accum, bnst);
        k_bn_apply<<<3125, 256, 0, stream>>>(accum, bnst, bnG + l * HID, bnB + l * HID,
                                             x, xbf);
    }
    k_mlp_mfma<<<256, 256, 0, stream>>>(xbf, W1f, W2f, b1, b2, W3, b3, out);
}

// Round 17
// 295.588 us; speedup vs baseline: 1.0994x; 1.0238x over previous
//
#include <hip/hip_runtime.h>
#include <hip/hip_bf16.h>

#define NND 50000
#define NCATS 3
#define VOC 1000
#define EDIM 16
#define NNUMF 16
#define FMAP 32
#define FIN 128          // 3*16 + 16 + 64
#define HID 64
#define NH 4
#define EB 400000
#define ETOT 450000      // EB + NND self loops
#define M1 256
#define M2 128
#define EPS_BN 1e-5f
#define NB 196           // ceil(NND/256)
#define YSTR 264         // LDS y-tile row stride in shorts (bank-spread)

typedef __attribute__((ext_vector_type(8))) short bf16x8;
typedef __attribute__((ext_vector_type(4))) float f32x4;

__device__ __forceinline__ float lrelu(float x) { return x > 0.f ? x : 0.2f * x; }

__device__ __forceinline__ unsigned short bfu(float f) {
    unsigned u = __float_as_uint(f);
    unsigned r = (u + 0x7FFFu + ((u >> 16) & 1u)) >> 16;
    return (unsigned short)r;
}
__device__ __forceinline__ float bf2f(unsigned short h) {
    return __uint_as_float((unsigned)h << 16);
}

// ================= CSR build (once; graph identical for both layers) =================
__global__ void k_zero_deg(int* __restrict__ deg) {
    int i = blockIdx.x * blockDim.x + threadIdx.x;
    if (i < NND) deg[i] = 0;
}

__global__ void k_count(const int* __restrict__ ei, int* __restrict__ deg) {
    int e = blockIdx.x * blockDim.x + threadIdx.x;
    if (e >= ETOT) return;
    int d = (e < EB) ? ei[EB + e] : e - EB;
    atomicAdd(&deg[d], 1);
}

__global__ __launch_bounds__(256) void k_bsum(const int* __restrict__ deg,
                                              int* __restrict__ bsum) {
    int i = blockIdx.x * 256 + threadIdx.x;
    int v = (i < NND) ? deg[i] : 0;
    #pragma unroll
    for (int ofs = 32; ofs; ofs >>= 1) v += __shfl_xor(v, ofs, 64);
    __shared__ int ws[4];
    if ((threadIdx.x & 63) == 0) ws[threadIdx.x >> 6] = v;
    __syncthreads();
    if (threadIdx.x == 0) bsum[blockIdx.x] = ws[0] + ws[1] + ws[2] + ws[3];
}

__global__ __launch_bounds__(256) void k_bscan(const int* __restrict__ bsum,
                                               int* __restrict__ bpre,
                                               int* __restrict__ off) {
    __shared__ int sh[256];
    const int t = threadIdx.x;
    int v = (t < NB) ? bsum[t] : 0;
    sh[t] = v;
    __syncthreads();
    for (int ofs = 1; ofs < 256; ofs <<= 1) {
        int u = (t >= ofs) ? sh[t - ofs] : 0;
        __syncthreads();
        sh[t] += u;
        __syncthreads();
    }
    if (t < NB) bpre[t] = sh[t] - v;
    if (t == 0) off[NND] = ETOT;
}

__global__ __launch_bounds__(256) void k_offsets(const int* __restrict__ deg,
                                                 const int* __restrict__ bpre,
                                                 int* __restrict__ off,
                                                 int* __restrict__ cur) {
    __shared__ int sh[256];
    const int t = threadIdx.x;
    const int i = blockIdx.x * 256 + t;
    int v = (i < NND) ? deg[i] : 0;
    sh[t] = v;
    __syncthreads();
    for (int ofs = 1; ofs < 256; ofs <<= 1) {
        int u = (t >= ofs) ? sh[t - ofs] : 0;
        __syncthreads();
        sh[t] += u;
        __syncthreads();
    }
    int excl = sh[t] - v + bpre[blockIdx.x];
    if (i < NND) { off[i] = excl; cur[i] = excl; }
}

__global__ void k_fill(const int* __restrict__ ei, int* __restrict__ cur,
                       int* __restrict__ srcs, int* __restrict__ edst) {
    int e = blockIdx.x * blockDim.x + threadIdx.x;
    if (e >= ETOT) return;
    int s, d;
    if (e < EB) { s = ei[e]; d = ei[EB + e]; } else { s = d = e - EB; }
    int p = atomicAdd(&cur[d], 1);
    srcs[p] = s;
    edst[p] = d;
}

// ===== pack W1/W2 (bf16), Ws (stacked gatW, hi+lo), pW (proj, hi+lo) into MFMA B-frag order =====
__global__ __launch_bounds__(256) void k_packw(
    const float* __restrict__ W1, const float* __restrict__ W2,
    const float* __restrict__ gatW, const float* __restrict__ pW,
    unsigned short* __restrict__ W1f, unsigned short* __restrict__ W2f,
    unsigned short* __restrict__ Wsf, unsigned short* __restrict__ Wsl,
    unsigned short* __restrict__ pWh, unsigned short* __restrict__ pWl)
{
    int i = blockIdx.x * 256 + threadIdx.x;
    if (i < 16384) {
        int j = i & 7, l = (i >> 3) & 63, t = i >> 9;
        int kc = t & 1, cb = t >> 1;
        int k = kc * 32 + ((l >> 4) * 8) + j, c = cb * 16 + (l & 15);
        W1f[i] = bfu(W1[k * 256 + c]);
    }
    if (i < 32768) {
        int j = i & 7, l = (i >> 3) & 63, t = i >> 9;
        int kc = t & 7, cb = t >> 3;
        int k = kc * 32 + ((l >> 4) * 8) + j, c = cb * 16 + (l & 15);
        W2f[i] = bfu(W2[k * 128 + c]);
    }
    if (i < 32768) {   // Ws: 2 layers x (4 cb x 8 kc); Ws[r][c] = W[r&63][(r>>6)*64+c]
        int j = i & 7, l = (i >> 3) & 63, t = (i >> 9) & 31, lay = i >> 14;
        int kc = t & 7, cb = t >> 3;
        int r = kc * 32 + ((l >> 4) * 8) + j, c = cb * 16 + (l & 15);
        float w = gatW[lay * 16384 + (r & 63) * 256 + (r >> 6) * 64 + c];
        unsigned short h = bfu(w);
        Wsf[i] = h;
        Wsl[i] = bfu(w - bf2f(h));
    }
    if (i < 8192) {    // pW: 4 cb x 4 kc; pW[k][c], k<128, c<64
        int j = i & 7, l = (i >> 3) & 63, t = i >> 9;
        int kc = t & 3, cb = t >> 2;
        int k = kc * 32 + ((l >> 4) * 8) + j, c = cb * 16 + (l & 15);
        float w = pW[k * 64 + c];
        unsigned short h = bfu(w);
        pWh[i] = h;
        pWl[i] = bfu(w - bf2f(h));
    }
}

// ====== K1: featurize + MFMA project (128 -> 64), split bf16, 64-node tiles ======
// writes fp32 x AND bf16 shadow xbf
__global__ __launch_bounds__(256) void k_feat_mfma(
    const int* __restrict__ x_cat, const float* __restrict__ x_num,
    const float* __restrict__ x_coord, const float* __restrict__ emb,
    const float* __restrict__ fB,
    const unsigned short* __restrict__ pWh, const unsigned short* __restrict__ pWl,
    const float* __restrict__ pb, float* __restrict__ xout,
    unsigned short* __restrict__ xbf)
{
    __shared__ __align__(16) unsigned short fh[64 * 128];  // 16 KB
    __shared__ __align__(16) unsigned short fl[64 * 128];  // 16 KB
    const int tid = threadIdx.x;
    const int lane = tid & 63, wid = tid >> 6;
    const int cl = lane & 15, lg = lane >> 4;
    const int nw = wid * 16;
    bf16x8 wfh[4][4], wfl[4][4];
    #pragma unroll
    for (int cb = 0; cb < 4; ++cb)
        #pragma unroll
        for (int kc = 0; kc < 4; ++kc) {
            wfh[cb][kc] = *(const bf16x8*)&pWh[(((cb << 2) + kc) * 64 + lane) * 8];
            wfl[cb][kc] = *(const bf16x8*)&pWl[(((cb << 2) + kc) * 64 + lane) * 8];
        }
    float pbr[4];
    #pragma unroll
    for (int cb = 0; cb < 4; ++cb) pbr[cb] = pb[cb * 16 + cl];
    const int ntiles = (NND + 63) / 64;   // 782
    for (int t = blockIdx.x; t < ntiles; t += gridDim.x) {
        const int n0 = t * 64;
        __syncthreads();
        for (int r = 0; r < 16; ++r) {
            const int row = nw + r;
            const int n = n0 + row;
            float v = 0.f, v2 = 0.f;
            if (n < NND) {
                if (lane < 48) {
                    int c = lane >> 4, j = lane & 15;
                    int idx = x_cat[n * NCATS + c];
                    v = emb[((size_t)c * VOC + idx) * EDIM + j];
                } else {
                    v = x_num[n * NNUMF + (lane - 48)];
                }
                float c0 = x_coord[n * 2 + 0], c1 = x_coord[n * 2 + 1];
                int f = lane & 31;
                float xp = 6.283185307179586f * (c0 * fB[f] + c1 * fB[FMAP + f]);
                v2 = (lane < 32) ? sinf(xp) : cosf(xp);
            }
            unsigned short h = bfu(v);
            fh[row * 128 + lane] = h;
            fl[row * 128 + lane] = bfu(v - bf2f(h));
            unsigned short h2 = bfu(v2);
            fh[row * 128 + 64 + lane] = h2;
            fl[row * 128 + 64 + lane] = bfu(v2 - bf2f(h2));
        }
        __syncthreads();
        bf16x8 afh[4], afl[4];
        #pragma unroll
        for (int kc = 0; kc < 4; ++kc) {
            afh[kc] = *(const bf16x8*)&fh[(nw + cl) * 128 + kc * 32 + lg * 8];
            afl[kc] = *(const bf16x8*)&fl[(nw + cl) * 128 + kc * 32 + lg * 8];
        }
        #pragma unroll
        for (int cb = 0; cb < 4; ++cb) {
            float bv = pbr[cb];
            f32x4 a = {bv, bv, bv, bv};
            #pragma unroll
            for (int kc = 0; kc < 4; ++kc)
                a = __builtin_amdgcn_mfma_f32_16x16x32_bf16(afl[kc], wfh[cb][kc], a, 0, 0, 0);
            #pragma unroll
            for (int kc = 0; kc < 4; ++kc)
                a = __builtin_amdgcn_mfma_f32_16x16x32_bf16(afh[kc], wfl[cb][kc], a, 0, 0, 0);
            #pragma unroll
            for (int kc = 0; kc < 4; ++kc)
                a = __builtin_amdgcn_mfma_f32_16x16x32_bf16(afh[kc], wfh[cb][kc], a, 0, 0, 0);
            #pragma unroll
            for (int r = 0; r < 4; ++r) {
                int n = n0 + nw + lg * 4 + r;
                if (n < NND) {
                    xout[(size_t)n * HID + cb * 16 + cl] = a[r];
                    xbf[(size_t)n * HID + cb * 16 + cl] = bfu(a[r]);
                }
            }
        }
    }
}

// ====== K2a: va for BOTH layers upfront (depends only on weights) ======
__global__ __launch_bounds__(512) void k_va2(
    const float* __restrict__ gatW, const float* __restrict__ attS,
    const float* __restrict__ attD, float* __restrict__ va2)
{
    const int lay = blockIdx.x;
    const float* W = gatW + (size_t)lay * 16384;
    const int t = threadIdx.x;
    const int k = t >> 3, q = t & 7, hh = q & 3;
    const float* a = ((q >= 4) ? attD : attS) + lay * NH * HID;
    float s = 0.f;
    #pragma unroll 8
    for (int d = 0; d < HID; ++d)
        s += W[k * 256 + hh * 64 + d] * a[hh * 64 + d];
    va2[lay * 512 + k * 8 + q] = s;
}

// ================= K2b: alphas from xbf (+ zero bnst replicas in blocks 0..7) =================
__global__ __launch_bounds__(256) void k_alpha2(
    const unsigned short* __restrict__ xbf, const float* __restrict__ va,
    float* __restrict__ alphS, float* __restrict__ alphD, float* __restrict__ bnst)
{
    __shared__ float vas[64 * 8];
    const int tid = threadIdx.x;
    if (blockIdx.x < 8) bnst[blockIdx.x * 256 + tid] = 0.f;
    for (int i = tid; i < 512; i += 256) vas[i] = va[i];
    __syncthreads();
    const int lane = tid & 63, wid = tid >> 6;
    const float4 vS = *(const float4*)&vas[lane * 8];
    const float4 vD = *(const float4*)&vas[lane * 8 + 4];
    for (int n = blockIdx.x * 4 + wid; n < NND; n += gridDim.x * 4) {
        float v = bf2f(xbf[(size_t)n * HID + lane]);
        float s0 = v * vS.x, s1 = v * vS.y, s2 = v * vS.z, s3 = v * vS.w;
        float d0 = v * vD.x, d1 = v * vD.y, d2 = v * vD.z, d3 = v * vD.w;
        #pragma unroll
        for (int ofs = 32; ofs; ofs >>= 1) {
            s0 += __shfl_xor(s0, ofs, 64); s1 += __shfl_xor(s1, ofs, 64);
            s2 += __shfl_xor(s2, ofs, 64); s3 += __shfl_xor(s3, ofs, 64);
            d0 += __shfl_xor(d0, ofs, 64); d1 += __shfl_xor(d1, ofs, 64);
            d2 += __shfl_xor(d2, ofs, 64); d3 += __shfl_xor(d3, ofs, 64);
        }
        if (lane == 0) {
            *(float4*)(alphS + (size_t)n * 4) = make_float4(s0, s1, s2, s3);
            *(float4*)(alphD + (size_t)n * 4) = make_float4(d0, d1, d2, d3);
        }
    }
}

// ====== K2c: per-edge softmax weights in CSR order (removes exp+gather from agg) ======
__global__ __launch_bounds__(256) void k_edge_w(
    const int* __restrict__ srcs, const int* __restrict__ edst,
    const float* __restrict__ alphS, const float* __restrict__ alphD,
    float4* __restrict__ ew)
{
    int e = blockIdx.x * 256 + threadIdx.x;
    if (e >= ETOT) return;
    int s = srcs[e], d = edst[e];
    float4 as = *(const float4*)(alphS + (size_t)s * 4);
    float4 ad = *(const float4*)(alphD + (size_t)d * 4);
    float4 w;
    w.x = __expf(lrelu(as.x + ad.x));
    w.y = __expf(lrelu(as.y + ad.y));
    w.z = __expf(lrelu(as.z + ad.z));
    w.w = __expf(lrelu(as.w + ad.w));
    ew[e] = w;
}

// ====== K3: FUSED single-pass aggregate (bf16 x gathers, precomputed w) + MFMA transform ======
__global__ __launch_bounds__(256) void k_agg_trans(
    const int* __restrict__ off, const int* __restrict__ srcs,
    const float4* __restrict__ ew,
    const unsigned short* __restrict__ xbf,
    const unsigned short* __restrict__ Wh, const unsigned short* __restrict__ Wl_,
    const float* __restrict__ gat_b, float* __restrict__ accum,
    float* __restrict__ bnst)
{
    __shared__ __align__(16) unsigned short ylh[16 * YSTR];  // 8.25 KB
    __shared__ __align__(16) unsigned short yll[16 * YSTR];  // 8.25 KB
    __shared__ float sred[2][4][16];
    const int tid = threadIdx.x;
    const int l16 = tid & 15, gi = tid >> 4;      // aggregation role: group gi, lane l16
    const int lane = tid & 63, wid = tid >> 6;    // transform role: cb = wid
    const int cl = lane & 15, lg = lane >> 4;
    const float bd = gat_b[wid * 16 + cl];
    float s1 = 0.f, s2 = 0.f;
    const int ngrp = NND / 16;   // 3125
    for (int g = blockIdx.x; g < ngrp; g += gridDim.x) {
        const int d = g * 16 + gi;               // always < NND
        // ---------- single-pass aggregation ----------
        const int o0 = off[d];
        const int deg = off[d + 1] - o0;
        float dn0 = 0.f, dn1 = 0.f, dn2 = 0.f, dn3 = 0.f;
        float ya[4][4];
        #pragma unroll
        for (int h = 0; h < 4; ++h)
            #pragma unroll
            for (int c = 0; c < 4; ++c) ya[h][c] = 0.f;
        for (int c0 = 0; c0 < deg; c0 += 16) {
            const int m = min(16, deg - c0);
            int sE = 0; float w0 = 0.f, w1 = 0.f, w2 = 0.f, w3 = 0.f;
            if (l16 < m) {
                sE = srcs[o0 + c0 + l16];
                float4 wv = ew[o0 + c0 + l16];
                w0 = wv.x; w1 = wv.y; w2 = wv.z; w3 = wv.w;
            }
            dn0 += w0; dn1 += w1; dn2 += w2; dn3 += w3;
            int j = 0;
            for (; j + 2 <= m; j += 2) {
                const int sj0 = __shfl(sE, j + 0, 16);
                const int sj1 = __shfl(sE, j + 1, 16);
                const ushort4 xu0 = *(const ushort4*)(xbf + (size_t)sj0 * HID + l16 * 4);
                const ushort4 xu1 = *(const ushort4*)(xbf + (size_t)sj1 * HID + l16 * 4);
                float a0 = __shfl(w0, j, 16), a1 = __shfl(w1, j, 16);
                float a2 = __shfl(w2, j, 16), a3 = __shfl(w3, j, 16);
                float x0 = bf2f(xu0.x), x1 = bf2f(xu0.y), x2 = bf2f(xu0.z), x3 = bf2f(xu0.w);
                ya[0][0] = fmaf(a0, x0, ya[0][0]); ya[0][1] = fmaf(a0, x1, ya[0][1]);
                ya[0][2] = fmaf(a0, x2, ya[0][2]); ya[0][3] = fmaf(a0, x3, ya[0][3]);
                ya[1][0] = fmaf(a1, x0, ya[1][0]); ya[1][1] = fmaf(a1, x1, ya[1][1]);
                ya[1][2] = fmaf(a1, x2, ya[1][2]); ya[1][3] = fmaf(a1, x3, ya[1][3]);
                ya[2][0] = fmaf(a2, x0, ya[2][0]); ya[2][1] = fmaf(a2, x1, ya[2][1]);
                ya[2][2] = fmaf(a2, x2, ya[2][2]); ya[2][3] = fmaf(a2, x3, ya[2][3]);
                ya[3][0] = fmaf(a3, x0, ya[3][0]); ya[3][1] = fmaf(a3, x1, ya[3][1]);
                ya[3][2] = fmaf(a3, x2, ya[3][2]); ya[3][3] = fmaf(a3, x3, ya[3][3]);
                a0 = __shfl(w0, j + 1, 16); a1 = __shfl(w1, j + 1, 16);
                a2 = __shfl(w2, j + 1, 16); a3 = __shfl(w3, j + 1, 16);
                x0 = bf2f(xu1.x); x1 = bf2f(xu1.y); x2 = bf2f(xu1.z); x3 = bf2f(xu1.w);
                ya[0][0] = fmaf(a0, x0, ya[0][0]); ya[0][1] = fmaf(a0, x1, ya[0][1]);
                ya[0][2] = fmaf(a0, x2, ya[0][2]); ya[0][3] = fmaf(a0, x3, ya[0][3]);
                ya[1][0] = fmaf(a1, x0, ya[1][0]); ya[1][1] = fmaf(a1, x1, ya[1][1]);
                ya[1][2] = fmaf(a1, x2, ya[1][2]); ya[1][3] = fmaf(a1, x3, ya[1][3]);
                ya[2][0] = fmaf(a2, x0, ya[2][0]); ya[2][1] = fmaf(a2, x1, ya[2][1]);
                ya[2][2] = fmaf(a2, x2, ya[2][2]); ya[2][3] = fmaf(a2, x3, ya[2][3]);
                ya[3][0] = fmaf(a3, x0, ya[3][0]); ya[3][1] = fmaf(a3, x1, ya[3][1]);
                ya[3][2] = fmaf(a3, x2, ya[3][2]); ya[3][3] = fmaf(a3, x3, ya[3][3]);
            }
            if (j < m) {
                const int sj0 = __shfl(sE, j, 16);
                const ushort4 xu0 = *(const ushort4*)(xbf + (size_t)sj0 * HID + l16 * 4);
                float a0 = __shfl(w0, j, 16), a1 = __shfl(w1, j, 16);
                float a2 = __shfl(w2, j, 16), a3 = __shfl(w3, j, 16);
                float x0 = bf2f(xu0.x), x1 = bf2f(xu0.y), x2 = bf2f(xu0.z), x3 = bf2f(xu0.w);
                ya[0][0] = fmaf(a0, x0, ya[0][0]); ya[0][1] = fmaf(a0, x1, ya[0][1]);
                ya[0][2] = fmaf(a0, x2, ya[0][2]); ya[0][3] = fmaf(a0, x3, ya[0][3]);
                ya[1][0] = fmaf(a1, x0, ya[1][0]); ya[1][1] = fmaf(a1, x1, ya[1][1]);
                ya[1][2] = fmaf(a1, x2, ya[1][2]); ya[1][3] = fmaf(a1, x3, ya[1][3]);
                ya[2][0] = fmaf(a2, x0, ya[2][0]); ya[2][1] = fmaf(a2, x1, ya[2][1]);
                ya[2][2] = fmaf(a2, x2, ya[2][2]); ya[2][3] = fmaf(a2, x3, ya[2][3]);
                ya[3][0] = fmaf(a3, x0, ya[3][0]); ya[3][1] = fmaf(a3, x1, ya[3][1]);
                ya[3][2] = fmaf(a3, x2, ya[3][2]); ya[3][3] = fmaf(a3, x3, ya[3][3]);
            }
        }
        #pragma unroll
        for (int ofs = 8; ofs; ofs >>= 1) {
            dn0 += __shfl_xor(dn0, ofs, 64); dn1 += __shfl_xor(dn1, ofs, 64);
            dn2 += __shfl_xor(dn2, ofs, 64); dn3 += __shfl_xor(dn3, ofs, 64);
        }
        {
            const float invh[4] = {
                __fdividef(1.f, dn0 + 1e-16f), __fdividef(1.f, dn1 + 1e-16f),
                __fdividef(1.f, dn2 + 1e-16f), __fdividef(1.f, dn3 + 1e-16f)};
            #pragma unroll
            for (int h = 0; h < 4; ++h) {
                ushort4 uh, ul;
                float v0 = ya[h][0] * invh[h]; uh.x = bfu(v0); ul.x = bfu(v0 - bf2f(uh.x));
                float v1 = ya[h][1] * invh[h]; uh.y = bfu(v1); ul.y = bfu(v1 - bf2f(uh.y));
                float v2 = ya[h][2] * invh[h]; uh.z = bfu(v2); ul.z = bfu(v2 - bf2f(uh.z));
                float v3 = ya[h][3] * invh[h]; uh.w = bfu(v3); ul.w = bfu(v3 - bf2f(uh.w));
                *(ushort4*)&ylh[gi * YSTR + h * 64 + l16 * 4] = uh;
                *(ushort4*)&yll[gi * YSTR + h * 64 + l16 * 4] = ul;
            }
        }
        __syncthreads();
        // ---------- transform phase (split bf16, 3 independent chains) ----------
        {
            bf16x8 afh[8], afl[8], wfh[8], wfl[8];
            #pragma unroll
            for (int kc = 0; kc < 8; ++kc) {
                afh[kc] = *(const bf16x8*)&ylh[cl * YSTR + kc * 32 + lg * 8];
                afl[kc] = *(const bf16x8*)&yll[cl * YSTR + kc * 32 + lg * 8];
                wfh[kc] = *(const bf16x8*)&Wh[(size_t)(((wid << 3) + kc) * 64 + lane) * 8];
                wfl[kc] = *(const bf16x8*)&Wl_[(size_t)(((wid << 3) + kc) * 64 + lane) * 8];
            }
            f32x4 a0 = {0.f, 0.f, 0.f, 0.f};
            f32x4 a1 = {0.f, 0.f, 0.f, 0.f};
            f32x4 a2 = {0.f, 0.f, 0.f, 0.f};
            #pragma unroll
            for (int kc = 0; kc < 8; ++kc) {
                a0 = __builtin_amdgcn_mfma_f32_16x16x32_bf16(afl[kc], wfh[kc], a0, 0, 0, 0);
                a1 = __builtin_amdgcn_mfma_f32_16x16x32_bf16(afh[kc], wfl[kc], a1, 0, 0, 0);
                a2 = __builtin_amdgcn_mfma_f32_16x16x32_bf16(afh[kc], wfh[kc], a2, 0, 0, 0);
            }
            const int n0 = g * 16;
            #pragma unroll
            for (int r = 0; r < 4; ++r) {
                float gv = (a0[r] + a1[r] + a2[r]) * 0.25f + bd;
                accum[(size_t)(n0 + lg * 4 + r) * HID + wid * 16 + cl] = gv;
                s1 += gv; s2 += gv * gv;
            }
        }
        __syncthreads();   // protect LDS before next group's writes
    }
    // ---------- BN-stats epilogue (8-replica atomics) ----------
    s1 += __shfl_xor(s1, 16, 64); s2 += __shfl_xor(s2, 16, 64);
    s1 += __shfl_xor(s1, 32, 64); s2 += __shfl_xor(s2, 32, 64);
    if (lane < 16) { sred[0][wid][cl] = s1; sred[1][wid][cl] = s2; }
    __syncthreads();
    if (tid < 64) {
        const int rep = (blockIdx.x & 7) * 256;
        atomicAdd(&bnst[rep + tid], sred[0][tid >> 4][tid & 15]);
        atomicAdd(&bnst[rep + 128 + tid], sred[1][tid >> 4][tid & 15]);
    }
}

// ========= K5: BN apply + relu + residual (sum 8 replicas; in place on x, + bf16 shadow) =========
__global__ void k_bn_apply(const float* __restrict__ accum, const float* __restrict__ bnst,
                           const float* __restrict__ gamma, const float* __restrict__ beta,
                           float* __restrict__ x, unsigned short* __restrict__ xbf)
{
    int i = blockIdx.x * blockDim.x + threadIdx.x;   // float4 index
    if (i >= NND * 16) return;
    int dg = (i & 15) * 4;
    float4 a = ((const float4*)accum)[i];
    float4 xv = ((float4*)x)[i];
    float r[4]; float av[4] = {a.x, a.y, a.z, a.w}; float xx[4] = {xv.x, xv.y, xv.z, xv.w};
    #pragma unroll
    for (int c = 0; c < 4; ++c) {
        int d = dg + c;
        float s1 = 0.f, s2 = 0.f;
        #pragma unroll
        for (int rep = 0; rep < 8; ++rep) {
            s1 += bnst[rep * 256 + d];
            s2 += bnst[rep * 256 + 128 + d];
        }
        float mu = s1 * (1.f / NND);
        float var = s2 * (1.f / NND) - mu * mu;
        float inv = rsqrtf(var + EPS_BN);
        float yv = (av[c] - mu) * inv * gamma[d] + beta[d];
        r[c] = fmaxf(yv, 0.f) + xx[c];
    }
    ((float4*)x)[i] = make_float4(r[0], r[1], r[2], r[3]);
    ushort4 u;
    u.x = bfu(r[0]); u.y = bfu(r[1]); u.z = bfu(r[2]); u.w = bfu(r[3]);
    *(ushort4*)(xbf + (size_t)i * 4) = u;
}

// ====== K6: fused MFMA MLP (stages x tile from bf16 shadow) ======
__global__ __launch_bounds__(256, 1) void k_mlp_mfma(
    const unsigned short* __restrict__ xbf,
    const unsigned short* __restrict__ W1f, const unsigned short* __restrict__ W2f,
    const float* __restrict__ b1, const float* __restrict__ b2,
    const float* __restrict__ W3, const float* __restrict__ b3,
    float* __restrict__ out)
{
    __shared__ __align__(16) unsigned short W1s[16384];  // 32 KB (frag order)
    __shared__ __align__(16) unsigned short W2s[32768];  // 64 KB (frag order)
    __shared__ __align__(16) unsigned short xs[64 * 64]; // 8 KB
    __shared__ __align__(16) unsigned short z1s[64 * 256]; // 32 KB
    __shared__ float b1s[256], b2s[128], w3s[128];
    const int tid = threadIdx.x;
    const int lane = tid & 63, wid = tid >> 6;
    {
        const uint4* s1 = (const uint4*)W1f; uint4* d1 = (uint4*)W1s;
        for (int i = tid; i < 2048; i += 256) d1[i] = s1[i];
        const uint4* s2 = (const uint4*)W2f; uint4* d2 = (uint4*)W2s;
        for (int i = tid; i < 4096; i += 256) d2[i] = s2[i];
        if (tid < 256) b1s[tid] = b1[tid];
        if (tid < 128) { b2s[tid] = b2[tid]; w3s[tid] = W3[tid]; }
    }
    const float bb3 = b3[0];
    const int nw = wid * 16;
    const int cl = lane & 15, lg = lane >> 4;
    const int ntiles = (NND + 63) / 64;
    for (int t = blockIdx.x; t < ntiles; t += gridDim.x) {
        const int n0 = t * 64;
        __syncthreads();
        #pragma unroll
        for (int q = 0; q < 2; ++q) {
            int i = q * 256 + tid;            // 0..511, 16 B each
            int row = i >> 3, k8 = (i & 7) * 8;
            int n = n0 + row;
            uint4 v = (n < NND) ? *(const uint4*)(xbf + (size_t)n * HID + k8)
                                : make_uint4(0u, 0u, 0u, 0u);
            *(uint4*)&xs[row * 64 + k8] = v;
        }
        __syncthreads();
        #pragma unroll 4
        for (int cb = 0; cb < 16; ++cb) {
            float bv = b1s[cb * 16 + cl];
            f32x4 a = {bv, bv, bv, bv};
            #pragma unroll
            for (int kc = 0; kc < 2; ++kc) {
                bf16x8 af = *(const bf16x8*)&xs[(nw + cl) * 64 + kc * 32 + lg * 8];
                bf16x8 bf = *(const bf16x8*)&W1s[(((cb << 1) + kc) * 64 + lane) * 8];
                a = __builtin_amdgcn_mfma_f32_16x16x32_bf16(af, bf, a, 0, 0, 0);
            }
            #pragma unroll
            for (int r = 0; r < 4; ++r)
                z1s[(nw + lg * 4 + r) * 256 + cb * 16 + cl] = bfu(fmaxf(a[r], 0.f));
        }
        __syncthreads();
        bf16x8 af2[8];
        #pragma unroll
        for (int kc = 0; kc < 8; ++kc)
            af2[kc] = *(const bf16x8*)&z1s[(nw + cl) * 256 + kc * 32 + lg * 8];
        float p0 = 0.f, p1 = 0.f, p2 = 0.f, p3 = 0.f;
        #pragma unroll
        for (int cb = 0; cb < 8; ++cb) {
            float bv = b2s[cb * 16 + cl];
            f32x4 a = {bv, bv, bv, bv};
            #pragma unroll
            for (int kc = 0; kc < 8; ++kc) {
                bf16x8 bf = *(const bf16x8*)&W2s[(((cb << 3) + kc) * 64 + lane) * 8];
                a = __builtin_amdgcn_mfma_f32_16x16x32_bf16(af2[kc], bf, a, 0, 0, 0);
            }
            float w3v = w3s[cb * 16 + cl];
            p0 = fmaf(fmaxf(a[0], 0.f), w3v, p0);
            p1 = fmaf(fmaxf(a[1], 0.f), w3v, p1);
            p2 = fmaf(fmaxf(a[2], 0.f), w3v, p2);
            p3 = fmaf(fmaxf(a[3], 0.f), w3v, p3);
        }
        #pragma unroll
        for (int ofs = 1; ofs <= 8; ofs <<= 1) {
            p0 += __shfl_xor(p0, ofs, 64); p1 += __shfl_xor(p1, ofs, 64);
            p2 += __shfl_xor(p2, ofs, 64); p3 += __shfl_xor(p3, ofs, 64);
        }
        if (cl == 0) {
            int base = n0 + nw + lg * 4;
            if (base + 0 < NND) out[base + 0] = p0 + bb3;
            if (base + 1 < NND) out[base + 1] = p1 + bb3;
            if (base + 2 < NND) out[base + 2] = p2 + bb3;
            if (base + 3 < NND) out[base + 3] = p3 + bb3;
        }
    }
}

extern "C" void kernel_launch(void* const* d_in, const int* in_sizes, int n_in,
                              void* d_out, int out_size, void* d_ws, size_t ws_size,
                              hipStream_t stream) {
    const int*   x_cat   = (const int*)  d_in[0];
    const float* x_num   = (const float*)d_in[1];
    const float* x_coord = (const float*)d_in[2];
    const int*   eidx    = (const int*)  d_in[3];
    const float* emb     = (const float*)d_in[4];
    const float* fB      = (const float*)d_in[5];
    const float* pW      = (const float*)d_in[6];
    const float* pb      = (const float*)d_in[7];
    const float* gatW    = (const float*)d_in[8];
    const float* attS    = (const float*)d_in[9];
    const float* attD    = (const float*)d_in[10];
    const float* gatB    = (const float*)d_in[11];
    const float* bnG     = (const float*)d_in[12];
    const float* bnB     = (const float*)d_in[13];
    const float* W1      = (const float*)d_in[14];
    const float* b1      = (const float*)d_in[15];
    const float* W2      = (const float*)d_in[16];
    const float* b2      = (const float*)d_in[17];
    const float* W3      = (const float*)d_in[18];
    const float* b3      = (const float*)d_in[19];
    float* out = (float*)d_out;

    char* p = (char*)d_ws;
    float* x     = (float*)p;  p += (size_t)NND * HID * 4;
    unsigned short* xbf = (unsigned short*)p; p += (size_t)NND * HID * 2;
    float* alphS = (float*)p;  p += (size_t)NND * NH * 4;
    float* alphD = (float*)p;  p += (size_t)NND * NH * 4;
    float* accum = (float*)p;  p += (size_t)NND * HID * 4;
    float* bnst  = (float*)p;  p += 8 * 256 * 4;
    float* va2   = (float*)p;  p += 1024 * 4;
    unsigned short* W1f = (unsigned short*)p; p += 16384 * 2;
    unsigned short* W2f = (unsigned short*)p; p += 32768 * 2;
    unsigned short* Wsf = (unsigned short*)p; p += 32768 * 2;
    unsigned short* Wsl = (unsigned short*)p; p += 32768 * 2;
    unsigned short* pWh = (unsigned short*)p; p += 8192 * 2;
    unsigned short* pWl = (unsigned short*)p; p += 8192 * 2;
    int*   deg   = (int*)p;    p += (size_t)NND * 4;
    int*   cur   = (int*)p;    p += (size_t)NND * 4;
    int*   off   = (int*)p;    p += (size_t)(NND + 1) * 4 + 4;
    int*   srcs  = (int*)p;    p += (size_t)ETOT * 4;
    int*   edst  = (int*)p;    p += (size_t)ETOT * 4;
    float4* ew   = (float4*)p; p += (size_t)ETOT * 16;
    int*   bsum  = (int*)p;    p += NB * 4;
    int*   bpre  = (int*)p;    p += NB * 4;

    // CSR build (graph constant across layers) + weight packing + va (both layers)
    k_zero_deg<<<NB, 256, 0, stream>>>(deg);
    k_count<<<(ETOT + 255) / 256, 256, 0, stream>>>(eidx, deg);
    k_bsum<<<NB, 256, 0, stream>>>(deg, bsum);
    k_bscan<<<1, 256, 0, stream>>>(bsum, bpre, off);
    k_offsets<<<NB, 256, 0, stream>>>(deg, bpre, off, cur);
    k_fill<<<(ETOT + 255) / 256, 256, 0, stream>>>(eidx, cur, srcs, edst);
    k_packw<<<192, 256, 0, stream>>>(W1, W2, gatW, pW, W1f, W2f, Wsf, Wsl, pWh, pWl);
    k_va2<<<2, 512, 0, stream>>>(gatW, attS, attD, va2);

    k_feat_mfma<<<512, 256, 0, stream>>>(x_cat, x_num, x_coord, emb, fB, pWh, pWl, pb,
                                         x, xbf);
    for (int l = 0; l < 2; ++l) {
        k_alpha2<<<2048, 256, 0, stream>>>(xbf, va2 + (size_t)l * 512, alphS, alphD, bnst);
        k_edge_w<<<(ETOT + 255) / 256, 256, 0, stream>>>(srcs, edst, alphS, alphD, ew);
        k_agg_trans<<<1024, 256, 0, stream>>>(off, srcs, ew, xbf,
                                              Wsf + (size_t)l * 16384,
                                              Wsl + (size_t)l * 16384,
                                              gatB + l * HID, accum, bnst);
        k_bn_apply<<<3125, 256, 0, stream>>>(accum, bnst, bnG + l * HID, bnB + l * HID,
                                             x, xbf);
    }
    k_mlp_mfma<<<256, 256, 0, stream>>>(xbf, W1f, W2f, b1, b2, W3, b3, out);
}

// Round 18
// 280.752 us; speedup vs baseline: 1.1575x; 1.0528x over previous
//
#include <hip/hip_runtime.h>
#include <hip/hip_bf16.h>

#define NND 50000
#define NCATS 3
#define VOC 1000
#define EDIM 16
#define NNUMF 16
#define FMAP 32
#define FIN 128          // 3*16 + 16 + 64
#define HID 64
#define NH 4
#define EB 400000
#define ETOT 450000      // EB + NND self loops
#define M1 256
#define M2 128
#define EPS_BN 1e-5f
#define NB 196           // ceil(NND/256)
#define YSTR 264         // LDS y-tile row stride in shorts (bank-spread)

typedef __attribute__((ext_vector_type(8))) short bf16x8;
typedef __attribute__((ext_vector_type(4))) float f32x4;

__device__ __forceinline__ float lrelu(float x) { return x > 0.f ? x : 0.2f * x; }

__device__ __forceinline__ unsigned short bfu(float f) {
    unsigned u = __float_as_uint(f);
    unsigned r = (u + 0x7FFFu + ((u >> 16) & 1u)) >> 16;
    return (unsigned short)r;
}
__device__ __forceinline__ float bf2f(unsigned short h) {
    return __uint_as_float((unsigned)h << 16);
}

// ================= CSR build (once; graph identical for both layers) =================
__global__ void k_zero_deg(int* __restrict__ deg) {
    int i = blockIdx.x * blockDim.x + threadIdx.x;
    if (i < NND) deg[i] = 0;
}

__global__ void k_count(const int* __restrict__ ei, int* __restrict__ deg) {
    int e = blockIdx.x * blockDim.x + threadIdx.x;
    if (e >= ETOT) return;
    int d = (e < EB) ? ei[EB + e] : e - EB;
    atomicAdd(&deg[d], 1);
}

__global__ __launch_bounds__(256) void k_bsum(const int* __restrict__ deg,
                                              int* __restrict__ bsum) {
    int i = blockIdx.x * 256 + threadIdx.x;
    int v = (i < NND) ? deg[i] : 0;
    #pragma unroll
    for (int ofs = 32; ofs; ofs >>= 1) v += __shfl_xor(v, ofs, 64);
    __shared__ int ws[4];
    if ((threadIdx.x & 63) == 0) ws[threadIdx.x >> 6] = v;
    __syncthreads();
    if (threadIdx.x == 0) bsum[blockIdx.x] = ws[0] + ws[1] + ws[2] + ws[3];
}

__global__ __launch_bounds__(256) void k_bscan(const int* __restrict__ bsum,
                                               int* __restrict__ bpre,
                                               int* __restrict__ off) {
    __shared__ int sh[256];
    const int t = threadIdx.x;
    int v = (t < NB) ? bsum[t] : 0;
    sh[t] = v;
    __syncthreads();
    for (int ofs = 1; ofs < 256; ofs <<= 1) {
        int u = (t >= ofs) ? sh[t - ofs] : 0;
        __syncthreads();
        sh[t] += u;
        __syncthreads();
    }
    if (t < NB) bpre[t] = sh[t] - v;
    if (t == 0) off[NND] = ETOT;
}

__global__ __launch_bounds__(256) void k_offsets(const int* __restrict__ deg,
                                                 const int* __restrict__ bpre,
                                                 int* __restrict__ off,
                                                 int* __restrict__ cur) {
    __shared__ int sh[256];
    const int t = threadIdx.x;
    const int i = blockIdx.x * 256 + t;
    int v = (i < NND) ? deg[i] : 0;
    sh[t] = v;
    __syncthreads();
    for (int ofs = 1; ofs < 256; ofs <<= 1) {
        int u = (t >= ofs) ? sh[t - ofs] : 0;
        __syncthreads();
        sh[t] += u;
        __syncthreads();
    }
    int excl = sh[t] - v + bpre[blockIdx.x];
    if (i < NND) { off[i] = excl; cur[i] = excl; }
}

__global__ void k_fill(const int* __restrict__ ei, int* __restrict__ cur,
                       int* __restrict__ srcs, int* __restrict__ edst) {
    int e = blockIdx.x * blockDim.x + threadIdx.x;
    if (e >= ETOT) return;
    int s, d;
    if (e < EB) { s = ei[e]; d = ei[EB + e]; } else { s = d = e - EB; }
    int p = atomicAdd(&cur[d], 1);
    srcs[p] = s;
    edst[p] = d;
}

// ===== pack W1/W2 (bf16), Ws (stacked gatW, hi+lo), pW (proj, hi+lo) into MFMA B-frag order =====
__global__ __launch_bounds__(256) void k_packw(
    const float* __restrict__ W1, const float* __restrict__ W2,
    const float* __restrict__ gatW, const float* __restrict__ pW,
    unsigned short* __restrict__ W1f, unsigned short* __restrict__ W2f,
    unsigned short* __restrict__ Wsf, unsigned short* __restrict__ Wsl,
    unsigned short* __restrict__ pWh, unsigned short* __restrict__ pWl)
{
    int i = blockIdx.x * 256 + threadIdx.x;
    if (i < 16384) {
        int j = i & 7, l = (i >> 3) & 63, t = i >> 9;
        int kc = t & 1, cb = t >> 1;
        int k = kc * 32 + ((l >> 4) * 8) + j, c = cb * 16 + (l & 15);
        W1f[i] = bfu(W1[k * 256 + c]);
    }
    if (i < 32768) {
        int j = i & 7, l = (i >> 3) & 63, t = i >> 9;
        int kc = t & 7, cb = t >> 3;
        int k = kc * 32 + ((l >> 4) * 8) + j, c = cb * 16 + (l & 15);
        W2f[i] = bfu(W2[k * 128 + c]);
    }
    if (i < 32768) {   // Ws: 2 layers x (4 cb x 8 kc); Ws[r][c] = W[r&63][(r>>6)*64+c]
        int j = i & 7, l = (i >> 3) & 63, t = (i >> 9) & 31, lay = i >> 14;
        int kc = t & 7, cb = t >> 3;
        int r = kc * 32 + ((l >> 4) * 8) + j, c = cb * 16 + (l & 15);
        float w = gatW[lay * 16384 + (r & 63) * 256 + (r >> 6) * 64 + c];
        unsigned short h = bfu(w);
        Wsf[i] = h;
        Wsl[i] = bfu(w - bf2f(h));
    }
    if (i < 8192) {    // pW: 4 cb x 4 kc; pW[k][c], k<128, c<64
        int j = i & 7, l = (i >> 3) & 63, t = i >> 9;
        int kc = t & 3, cb = t >> 2;
        int k = kc * 32 + ((l >> 4) * 8) + j, c = cb * 16 + (l & 15);
        float w = pW[k * 64 + c];
        unsigned short h = bfu(w);
        pWh[i] = h;
        pWl[i] = bfu(w - bf2f(h));
    }
}

// ====== K1: featurize + MFMA project (128 -> 64), split bf16, 64-node tiles ======
__global__ __launch_bounds__(256) void k_feat_mfma(
    const int* __restrict__ x_cat, const float* __restrict__ x_num,
    const float* __restrict__ x_coord, const float* __restrict__ emb,
    const float* __restrict__ fB,
    const unsigned short* __restrict__ pWh, const unsigned short* __restrict__ pWl,
    const float* __restrict__ pb, float* __restrict__ xout,
    unsigned short* __restrict__ xbf)
{
    __shared__ __align__(16) unsigned short fh[64 * 128];  // 16 KB
    __shared__ __align__(16) unsigned short fl[64 * 128];  // 16 KB
    const int tid = threadIdx.x;
    const int lane = tid & 63, wid = tid >> 6;
    const int cl = lane & 15, lg = lane >> 4;
    const int nw = wid * 16;
    bf16x8 wfh[4][4], wfl[4][4];
    #pragma unroll
    for (int cb = 0; cb < 4; ++cb)
        #pragma unroll
        for (int kc = 0; kc < 4; ++kc) {
            wfh[cb][kc] = *(const bf16x8*)&pWh[(((cb << 2) + kc) * 64 + lane) * 8];
            wfl[cb][kc] = *(const bf16x8*)&pWl[(((cb << 2) + kc) * 64 + lane) * 8];
        }
    float pbr[4];
    #pragma unroll
    for (int cb = 0; cb < 4; ++cb) pbr[cb] = pb[cb * 16 + cl];
    const int ntiles = (NND + 63) / 64;   // 782
    for (int t = blockIdx.x; t < ntiles; t += gridDim.x) {
        const int n0 = t * 64;
        __syncthreads();
        for (int r = 0; r < 16; ++r) {
            const int row = nw + r;
            const int n = n0 + row;
            float v = 0.f, v2 = 0.f;
            if (n < NND) {
                if (lane < 48) {
                    int c = lane >> 4, j = lane & 15;
                    int idx = x_cat[n * NCATS + c];
                    v = emb[((size_t)c * VOC + idx) * EDIM + j];
                } else {
                    v = x_num[n * NNUMF + (lane - 48)];
                }
                float c0 = x_coord[n * 2 + 0], c1 = x_coord[n * 2 + 1];
                int f = lane & 31;
                float xp = 6.283185307179586f * (c0 * fB[f] + c1 * fB[FMAP + f]);
                v2 = (lane < 32) ? sinf(xp) : cosf(xp);
            }
            unsigned short h = bfu(v);
            fh[row * 128 + lane] = h;
            fl[row * 128 + lane] = bfu(v - bf2f(h));
            unsigned short h2 = bfu(v2);
            fh[row * 128 + 64 + lane] = h2;
            fl[row * 128 + 64 + lane] = bfu(v2 - bf2f(h2));
        }
        __syncthreads();
        bf16x8 afh[4], afl[4];
        #pragma unroll
        for (int kc = 0; kc < 4; ++kc) {
            afh[kc] = *(const bf16x8*)&fh[(nw + cl) * 128 + kc * 32 + lg * 8];
            afl[kc] = *(const bf16x8*)&fl[(nw + cl) * 128 + kc * 32 + lg * 8];
        }
        #pragma unroll
        for (int cb = 0; cb < 4; ++cb) {
            float bv = pbr[cb];
            f32x4 a = {bv, bv, bv, bv};
            #pragma unroll
            for (int kc = 0; kc < 4; ++kc)
                a = __builtin_amdgcn_mfma_f32_16x16x32_bf16(afl[kc], wfh[cb][kc], a, 0, 0, 0);
            #pragma unroll
            for (int kc = 0; kc < 4; ++kc)
                a = __builtin_amdgcn_mfma_f32_16x16x32_bf16(afh[kc], wfl[cb][kc], a, 0, 0, 0);
            #pragma unroll
            for (int kc = 0; kc < 4; ++kc)
                a = __builtin_amdgcn_mfma_f32_16x16x32_bf16(afh[kc], wfh[cb][kc], a, 0, 0, 0);
            #pragma unroll
            for (int r = 0; r < 4; ++r) {
                int n = n0 + nw + lg * 4 + r;
                if (n < NND) {
                    xout[(size_t)n * HID + cb * 16 + cl] = a[r];
                    xbf[(size_t)n * HID + cb * 16 + cl] = bfu(a[r]);
                }
            }
        }
    }
}

// ====== K2a: va for BOTH layers upfront (depends only on weights) ======
__global__ __launch_bounds__(512) void k_va2(
    const float* __restrict__ gatW, const float* __restrict__ attS,
    const float* __restrict__ attD, float* __restrict__ va2)
{
    const int lay = blockIdx.x;
    const float* W = gatW + (size_t)lay * 16384;
    const int t = threadIdx.x;
    const int k = t >> 3, q = t & 7, hh = q & 3;
    const float* a = ((q >= 4) ? attD : attS) + lay * NH * HID;
    float s = 0.f;
    #pragma unroll 8
    for (int d = 0; d < HID; ++d)
        s += W[k * 256 + hh * 64 + d] * a[hh * 64 + d];
    va2[lay * 512 + k * 8 + q] = s;
}

// ================= K2b: alphas from xbf (first layer only) =================
__global__ __launch_bounds__(256) void k_alpha2(
    const unsigned short* __restrict__ xbf, const float* __restrict__ va,
    float* __restrict__ alphS, float* __restrict__ alphD)
{
    __shared__ float vas[64 * 8];
    const int tid = threadIdx.x;
    for (int i = tid; i < 512; i += 256) vas[i] = va[i];
    __syncthreads();
    const int lane = tid & 63, wid = tid >> 6;
    const float4 vS = *(const float4*)&vas[lane * 8];
    const float4 vD = *(const float4*)&vas[lane * 8 + 4];
    for (int n = blockIdx.x * 4 + wid; n < NND; n += gridDim.x * 4) {
        float v = bf2f(xbf[(size_t)n * HID + lane]);
        float s0 = v * vS.x, s1 = v * vS.y, s2 = v * vS.z, s3 = v * vS.w;
        float d0 = v * vD.x, d1 = v * vD.y, d2 = v * vD.z, d3 = v * vD.w;
        #pragma unroll
        for (int ofs = 32; ofs; ofs >>= 1) {
            s0 += __shfl_xor(s0, ofs, 64); s1 += __shfl_xor(s1, ofs, 64);
            s2 += __shfl_xor(s2, ofs, 64); s3 += __shfl_xor(s3, ofs, 64);
            d0 += __shfl_xor(d0, ofs, 64); d1 += __shfl_xor(d1, ofs, 64);
            d2 += __shfl_xor(d2, ofs, 64); d3 += __shfl_xor(d3, ofs, 64);
        }
        if (lane == 0) {
            *(float4*)(alphS + (size_t)n * 4) = make_float4(s0, s1, s2, s3);
            *(float4*)(alphD + (size_t)n * 4) = make_float4(d0, d1, d2, d3);
        }
    }
}

// ====== K2c: per-edge softmax weights (bf16x4) in CSR order + zero bnst ======
__global__ __launch_bounds__(256) void k_edge_w(
    const int* __restrict__ srcs, const int* __restrict__ edst,
    const float* __restrict__ alphS, const float* __restrict__ alphD,
    ushort4* __restrict__ ewb, float* __restrict__ bnst)
{
    int e = blockIdx.x * 256 + threadIdx.x;
    if (blockIdx.x < 8) bnst[blockIdx.x * 256 + threadIdx.x] = 0.f;
    if (e >= ETOT) return;
    int s = srcs[e], d = edst[e];
    float4 as = *(const float4*)(alphS + (size_t)s * 4);
    float4 ad = *(const float4*)(alphD + (size_t)d * 4);
    ushort4 w;
    w.x = bfu(__expf(lrelu(as.x + ad.x)));
    w.y = bfu(__expf(lrelu(as.y + ad.y)));
    w.z = bfu(__expf(lrelu(as.z + ad.z)));
    w.w = bfu(__expf(lrelu(as.w + ad.w)));
    ewb[e] = w;
}

// ====== K3: FUSED single-pass aggregate (bf16 x gathers, bf16 w) + MFMA transform ======
__global__ __launch_bounds__(256) void k_agg_trans(
    const int* __restrict__ off, const int* __restrict__ srcs,
    const ushort4* __restrict__ ewb,
    const unsigned short* __restrict__ xbf,
    const unsigned short* __restrict__ Wh, const unsigned short* __restrict__ Wl_,
    const float* __restrict__ gat_b, float* __restrict__ accum,
    float* __restrict__ bnst)
{
    __shared__ __align__(16) unsigned short ylh[16 * YSTR];  // 8.25 KB
    __shared__ __align__(16) unsigned short yll[16 * YSTR];  // 8.25 KB
    __shared__ float sred[2][4][16];
    const int tid = threadIdx.x;
    const int l16 = tid & 15, gi = tid >> 4;      // aggregation role: group gi, lane l16
    const int lane = tid & 63, wid = tid >> 6;    // transform role: cb = wid
    const int cl = lane & 15, lg = lane >> 4;
    const float bd = gat_b[wid * 16 + cl];
    float s1 = 0.f, s2 = 0.f;
    const int ngrp = NND / 16;   // 3125
    for (int g = blockIdx.x; g < ngrp; g += gridDim.x) {
        const int d = g * 16 + gi;               // always < NND
        const int o0 = off[d];
        const int deg = off[d + 1] - o0;
        float dn0 = 0.f, dn1 = 0.f, dn2 = 0.f, dn3 = 0.f;
        float ya[4][4];
        #pragma unroll
        for (int h = 0; h < 4; ++h)
            #pragma unroll
            for (int c = 0; c < 4; ++c) ya[h][c] = 0.f;
        for (int c0 = 0; c0 < deg; c0 += 16) {
            const int m = min(16, deg - c0);
            int sE = 0; float w0 = 0.f, w1 = 0.f, w2 = 0.f, w3 = 0.f;
            if (l16 < m) {
                sE = srcs[o0 + c0 + l16];
                ushort4 wv = ewb[o0 + c0 + l16];
                w0 = bf2f(wv.x); w1 = bf2f(wv.y); w2 = bf2f(wv.z); w3 = bf2f(wv.w);
            }
            dn0 += w0; dn1 += w1; dn2 += w2; dn3 += w3;
            int j = 0;
            for (; j + 2 <= m; j += 2) {
                const int sj0 = __shfl(sE, j + 0, 16);
                const int sj1 = __shfl(sE, j + 1, 16);
                const ushort4 xu0 = *(const ushort4*)(xbf + (size_t)sj0 * HID + l16 * 4);
                const ushort4 xu1 = *(const ushort4*)(xbf + (size_t)sj1 * HID + l16 * 4);
                float a0 = __shfl(w0, j, 16), a1 = __shfl(w1, j, 16);
                float a2 = __shfl(w2, j, 16), a3 = __shfl(w3, j, 16);
                float x0 = bf2f(xu0.x), x1 = bf2f(xu0.y), x2 = bf2f(xu0.z), x3 = bf2f(xu0.w);
                ya[0][0] = fmaf(a0, x0, ya[0][0]); ya[0][1] = fmaf(a0, x1, ya[0][1]);
                ya[0][2] = fmaf(a0, x2, ya[0][2]); ya[0][3] = fmaf(a0, x3, ya[0][3]);
                ya[1][0] = fmaf(a1, x0, ya[1][0]); ya[1][1] = fmaf(a1, x1, ya[1][1]);
                ya[1][2] = fmaf(a1, x2, ya[1][2]); ya[1][3] = fmaf(a1, x3, ya[1][3]);
                ya[2][0] = fmaf(a2, x0, ya[2][0]); ya[2][1] = fmaf(a2, x1, ya[2][1]);
                ya[2][2] = fmaf(a2, x2, ya[2][2]); ya[2][3] = fmaf(a2, x3, ya[2][3]);
                ya[3][0] = fmaf(a3, x0, ya[3][0]); ya[3][1] = fmaf(a3, x1, ya[3][1]);
                ya[3][2] = fmaf(a3, x2, ya[3][2]); ya[3][3] = fmaf(a3, x3, ya[3][3]);
                a0 = __shfl(w0, j + 1, 16); a1 = __shfl(w1, j + 1, 16);
                a2 = __shfl(w2, j + 1, 16); a3 = __shfl(w3, j + 1, 16);
                x0 = bf2f(xu1.x); x1 = bf2f(xu1.y); x2 = bf2f(xu1.z); x3 = bf2f(xu1.w);
                ya[0][0] = fmaf(a0, x0, ya[0][0]); ya[0][1] = fmaf(a0, x1, ya[0][1]);
                ya[0][2] = fmaf(a0, x2, ya[0][2]); ya[0][3] = fmaf(a0, x3, ya[0][3]);
                ya[1][0] = fmaf(a1, x0, ya[1][0]); ya[1][1] = fmaf(a1, x1, ya[1][1]);
                ya[1][2] = fmaf(a1, x2, ya[1][2]); ya[1][3] = fmaf(a1, x3, ya[1][3]);
                ya[2][0] = fmaf(a2, x0, ya[2][0]); ya[2][1] = fmaf(a2, x1, ya[2][1]);
                ya[2][2] = fmaf(a2, x2, ya[2][2]); ya[2][3] = fmaf(a2, x3, ya[2][3]);
                ya[3][0] = fmaf(a3, x0, ya[3][0]); ya[3][1] = fmaf(a3, x1, ya[3][1]);
                ya[3][2] = fmaf(a3, x2, ya[3][2]); ya[3][3] = fmaf(a3, x3, ya[3][3]);
            }
            if (j < m) {
                const int sj0 = __shfl(sE, j, 16);
                const ushort4 xu0 = *(const ushort4*)(xbf + (size_t)sj0 * HID + l16 * 4);
                float a0 = __shfl(w0, j, 16), a1 = __shfl(w1, j, 16);
                float a2 = __shfl(w2, j, 16), a3 = __shfl(w3, j, 16);
                float x0 = bf2f(xu0.x), x1 = bf2f(xu0.y), x2 = bf2f(xu0.z), x3 = bf2f(xu0.w);
                ya[0][0] = fmaf(a0, x0, ya[0][0]); ya[0][1] = fmaf(a0, x1, ya[0][1]);
                ya[0][2] = fmaf(a0, x2, ya[0][2]); ya[0][3] = fmaf(a0, x3, ya[0][3]);
                ya[1][0] = fmaf(a1, x0, ya[1][0]); ya[1][1] = fmaf(a1, x1, ya[1][1]);
                ya[1][2] = fmaf(a1, x2, ya[1][2]); ya[1][3] = fmaf(a1, x3, ya[1][3]);
                ya[2][0] = fmaf(a2, x0, ya[2][0]); ya[2][1] = fmaf(a2, x1, ya[2][1]);
                ya[2][2] = fmaf(a2, x2, ya[2][2]); ya[2][3] = fmaf(a2, x3, ya[2][3]);
                ya[3][0] = fmaf(a3, x0, ya[3][0]); ya[3][1] = fmaf(a3, x1, ya[3][1]);
                ya[3][2] = fmaf(a3, x2, ya[3][2]); ya[3][3] = fmaf(a3, x3, ya[3][3]);
            }
        }
        #pragma unroll
        for (int ofs = 8; ofs; ofs >>= 1) {
            dn0 += __shfl_xor(dn0, ofs, 64); dn1 += __shfl_xor(dn1, ofs, 64);
            dn2 += __shfl_xor(dn2, ofs, 64); dn3 += __shfl_xor(dn3, ofs, 64);
        }
        {
            const float invh[4] = {
                __fdividef(1.f, dn0 + 1e-16f), __fdividef(1.f, dn1 + 1e-16f),
                __fdividef(1.f, dn2 + 1e-16f), __fdividef(1.f, dn3 + 1e-16f)};
            #pragma unroll
            for (int h = 0; h < 4; ++h) {
                ushort4 uh, ul;
                float v0 = ya[h][0] * invh[h]; uh.x = bfu(v0); ul.x = bfu(v0 - bf2f(uh.x));
                float v1 = ya[h][1] * invh[h]; uh.y = bfu(v1); ul.y = bfu(v1 - bf2f(uh.y));
                float v2 = ya[h][2] * invh[h]; uh.z = bfu(v2); ul.z = bfu(v2 - bf2f(uh.z));
                float v3 = ya[h][3] * invh[h]; uh.w = bfu(v3); ul.w = bfu(v3 - bf2f(uh.w));
                *(ushort4*)&ylh[gi * YSTR + h * 64 + l16 * 4] = uh;
                *(ushort4*)&yll[gi * YSTR + h * 64 + l16 * 4] = ul;
            }
        }
        __syncthreads();
        // ---------- transform phase (split bf16, 3 independent chains) ----------
        {
            bf16x8 afh[8], afl[8], wfh[8], wfl[8];
            #pragma unroll
            for (int kc = 0; kc < 8; ++kc) {
                afh[kc] = *(const bf16x8*)&ylh[cl * YSTR + kc * 32 + lg * 8];
                afl[kc] = *(const bf16x8*)&yll[cl * YSTR + kc * 32 + lg * 8];
                wfh[kc] = *(const bf16x8*)&Wh[(size_t)(((wid << 3) + kc) * 64 + lane) * 8];
                wfl[kc] = *(const bf16x8*)&Wl_[(size_t)(((wid << 3) + kc) * 64 + lane) * 8];
            }
            f32x4 a0 = {0.f, 0.f, 0.f, 0.f};
            f32x4 a1 = {0.f, 0.f, 0.f, 0.f};
            f32x4 a2 = {0.f, 0.f, 0.f, 0.f};
            #pragma unroll
            for (int kc = 0; kc < 8; ++kc) {
                a0 = __builtin_amdgcn_mfma_f32_16x16x32_bf16(afl[kc], wfh[kc], a0, 0, 0, 0);
                a1 = __builtin_amdgcn_mfma_f32_16x16x32_bf16(afh[kc], wfl[kc], a1, 0, 0, 0);
                a2 = __builtin_amdgcn_mfma_f32_16x16x32_bf16(afh[kc], wfh[kc], a2, 0, 0, 0);
            }
            const int n0 = g * 16;
            #pragma unroll
            for (int r = 0; r < 4; ++r) {
                float gv = (a0[r] + a1[r] + a2[r]) * 0.25f + bd;
                accum[(size_t)(n0 + lg * 4 + r) * HID + wid * 16 + cl] = gv;
                s1 += gv; s2 += gv * gv;
            }
        }
        __syncthreads();   // protect LDS before next group's writes
    }
    // ---------- BN-stats epilogue (8-replica atomics) ----------
    s1 += __shfl_xor(s1, 16, 64); s2 += __shfl_xor(s2, 16, 64);
    s1 += __shfl_xor(s1, 32, 64); s2 += __shfl_xor(s2, 32, 64);
    if (lane < 16) { sred[0][wid][cl] = s1; sred[1][wid][cl] = s2; }
    __syncthreads();
    if (tid < 64) {
        const int rep = (blockIdx.x & 7) * 256;
        atomicAdd(&bnst[rep + tid], sred[0][tid >> 4][tid & 15]);
        atomicAdd(&bnst[rep + 128 + tid], sred[1][tid >> 4][tid & 15]);
    }
}

// ========= K5: FUSED BN apply + relu + residual + (optional) next-layer alphas =========
__global__ __launch_bounds__(256) void k_bn_alpha(
    const float* __restrict__ accum, const float* __restrict__ bnst,
    const float* __restrict__ gamma, const float* __restrict__ beta,
    float* __restrict__ x, unsigned short* __restrict__ xbf,
    const float* __restrict__ va, float* __restrict__ alphS,
    float* __restrict__ alphD, int doAlpha)
{
    __shared__ float vas[64 * 8];
    const int tid = threadIdx.x;
    for (int i = tid; i < 512; i += 256) vas[i] = va[i];
    __syncthreads();
    const int lane = tid & 63, wid = tid >> 6;
    const float4 vS = *(const float4*)&vas[lane * 8];
    const float4 vD = *(const float4*)&vas[lane * 8 + 4];
    float s1 = 0.f, s2 = 0.f;
    #pragma unroll
    for (int rep = 0; rep < 8; ++rep) {
        s1 += bnst[rep * 256 + lane];
        s2 += bnst[rep * 256 + 128 + lane];
    }
    const float mu = s1 * (1.f / NND);
    const float var = s2 * (1.f / NND) - mu * mu;
    const float inv = rsqrtf(var + EPS_BN);
    const float ga = gamma[lane], be = beta[lane];
    for (int n = blockIdx.x * 4 + wid; n < NND; n += gridDim.x * 4) {
        float av = accum[(size_t)n * HID + lane];
        float xv = x[(size_t)n * HID + lane];
        float r = fmaxf((av - mu) * inv * ga + be, 0.f) + xv;
        x[(size_t)n * HID + lane] = r;
        unsigned short h = bfu(r);
        xbf[(size_t)n * HID + lane] = h;
        if (doAlpha) {
            float v = bf2f(h);
            float s0 = v * vS.x, t1 = v * vS.y, t2 = v * vS.z, t3 = v * vS.w;
            float d0 = v * vD.x, d1 = v * vD.y, d2 = v * vD.z, d3 = v * vD.w;
            #pragma unroll
            for (int ofs = 32; ofs; ofs >>= 1) {
                s0 += __shfl_xor(s0, ofs, 64); t1 += __shfl_xor(t1, ofs, 64);
                t2 += __shfl_xor(t2, ofs, 64); t3 += __shfl_xor(t3, ofs, 64);
                d0 += __shfl_xor(d0, ofs, 64); d1 += __shfl_xor(d1, ofs, 64);
                d2 += __shfl_xor(d2, ofs, 64); d3 += __shfl_xor(d3, ofs, 64);
            }
            if (lane == 0) {
                *(float4*)(alphS + (size_t)n * 4) = make_float4(s0, t1, t2, t3);
                *(float4*)(alphD + (size_t)n * 4) = make_float4(d0, d1, d2, d3);
            }
        }
    }
}

// ====== K6: fused MFMA MLP (stages x tile from bf16 shadow) ======
__global__ __launch_bounds__(256, 1) void k_mlp_mfma(
    const unsigned short* __restrict__ xbf,
    const unsigned short* __restrict__ W1f, const unsigned short* __restrict__ W2f,
    const float* __restrict__ b1, const float* __restrict__ b2,
    const float* __restrict__ W3, const float* __restrict__ b3,
    float* __restrict__ out)
{
    __shared__ __align__(16) unsigned short W1s[16384];  // 32 KB (frag order)
    __shared__ __align__(16) unsigned short W2s[32768];  // 64 KB (frag order)
    __shared__ __align__(16) unsigned short xs[64 * 64]; // 8 KB
    __shared__ __align__(16) unsigned short z1s[64 * 256]; // 32 KB
    __shared__ float b1s[256], b2s[128], w3s[128];
    const int tid = threadIdx.x;
    const int lane = tid & 63, wid = tid >> 6;
    {
        const uint4* s1 = (const uint4*)W1f; uint4* d1 = (uint4*)W1s;
        for (int i = tid; i < 2048; i += 256) d1[i] = s1[i];
        const uint4* s2 = (const uint4*)W2f; uint4* d2 = (uint4*)W2s;
        for (int i = tid; i < 4096; i += 256) d2[i] = s2[i];
        if (tid < 256) b1s[tid] = b1[tid];
        if (tid < 128) { b2s[tid] = b2[tid]; w3s[tid] = W3[tid]; }
    }
    const float bb3 = b3[0];
    const int nw = wid * 16;
    const int cl = lane & 15, lg = lane >> 4;
    const int ntiles = (NND + 63) / 64;
    for (int t = blockIdx.x; t < ntiles; t += gridDim.x) {
        const int n0 = t * 64;
        __syncthreads();
        #pragma unroll
        for (int q = 0; q < 2; ++q) {
            int i = q * 256 + tid;            // 0..511, 16 B each
            int row = i >> 3, k8 = (i & 7) * 8;
            int n = n0 + row;
            uint4 v = (n < NND) ? *(const uint4*)(xbf + (size_t)n * HID + k8)
                                : make_uint4(0u, 0u, 0u, 0u);
            *(uint4*)&xs[row * 64 + k8] = v;
        }
        __syncthreads();
        #pragma unroll 4
        for (int cb = 0; cb < 16; ++cb) {
            float bv = b1s[cb * 16 + cl];
            f32x4 a = {bv, bv, bv, bv};
            #pragma unroll
            for (int kc = 0; kc < 2; ++kc) {
                bf16x8 af = *(const bf16x8*)&xs[(nw + cl) * 64 + kc * 32 + lg * 8];
                bf16x8 bf = *(const bf16x8*)&W1s[(((cb << 1) + kc) * 64 + lane) * 8];
                a = __builtin_amdgcn_mfma_f32_16x16x32_bf16(af, bf, a, 0, 0, 0);
            }
            #pragma unroll
            for (int r = 0; r < 4; ++r)
                z1s[(nw + lg * 4 + r) * 256 + cb * 16 + cl] = bfu(fmaxf(a[r], 0.f));
        }
        __syncthreads();
        bf16x8 af2[8];
        #pragma unroll
        for (int kc = 0; kc < 8; ++kc)
            af2[kc] = *(const bf16x8*)&z1s[(nw + cl) * 256 + kc * 32 + lg * 8];
        float p0 = 0.f, p1 = 0.f, p2 = 0.f, p3 = 0.f;
        #pragma unroll
        for (int cb = 0; cb < 8; ++cb) {
            float bv = b2s[cb * 16 + cl];
            f32x4 a = {bv, bv, bv, bv};
            #pragma unroll
            for (int kc = 0; kc < 8; ++kc) {
                bf16x8 bf = *(const bf16x8*)&W2s[(((cb << 3) + kc) * 64 + lane) * 8];
                a = __builtin_amdgcn_mfma_f32_16x16x32_bf16(af2[kc], bf, a, 0, 0, 0);
            }
            float w3v = w3s[cb * 16 + cl];
            p0 = fmaf(fmaxf(a[0], 0.f), w3v, p0);
            p1 = fmaf(fmaxf(a[1], 0.f), w3v, p1);
            p2 = fmaf(fmaxf(a[2], 0.f), w3v, p2);
            p3 = fmaf(fmaxf(a[3], 0.f), w3v, p3);
        }
        #pragma unroll
        for (int ofs = 1; ofs <= 8; ofs <<= 1) {
            p0 += __shfl_xor(p0, ofs, 64); p1 += __shfl_xor(p1, ofs, 64);
            p2 += __shfl_xor(p2, ofs, 64); p3 += __shfl_xor(p3, ofs, 64);
        }
        if (cl == 0) {
            int base = n0 + nw + lg * 4;
            if (base + 0 < NND) out[base + 0] = p0 + bb3;
            if (base + 1 < NND) out[base + 1] = p1 + bb3;
            if (base + 2 < NND) out[base + 2] = p2 + bb3;
            if (base + 3 < NND) out[base + 3] = p3 + bb3;
        }
    }
}

extern "C" void kernel_launch(void* const* d_in, const int* in_sizes, int n_in,
                              void* d_out, int out_size, void* d_ws, size_t ws_size,
                              hipStream_t stream) {
    const int*   x_cat   = (const int*)  d_in[0];
    const float* x_num   = (const float*)d_in[1];
    const float* x_coord = (const float*)d_in[2];
    const int*   eidx    = (const int*)  d_in[3];
    const float* emb     = (const float*)d_in[4];
    const float* fB      = (const float*)d_in[5];
    const float* pW      = (const float*)d_in[6];
    const float* pb      = (const float*)d_in[7];
    const float* gatW    = (const float*)d_in[8];
    const float* attS    = (const float*)d_in[9];
    const float* attD    = (const float*)d_in[10];
    const float* gatB    = (const float*)d_in[11];
    const float* bnG     = (const float*)d_in[12];
    const float* bnB     = (const float*)d_in[13];
    const float* W1      = (const float*)d_in[14];
    const float* b1      = (const float*)d_in[15];
    const float* W2      = (const float*)d_in[16];
    const float* b2      = (const float*)d_in[17];
    const float* W3      = (const float*)d_in[18];
    const float* b3      = (const float*)d_in[19];
    float* out = (float*)d_out;

    char* p = (char*)d_ws;
    float* x     = (float*)p;  p += (size_t)NND * HID * 4;
    unsigned short* xbf = (unsigned short*)p; p += (size_t)NND * HID * 2;
    float* alphS = (float*)p;  p += (size_t)NND * NH * 4;
    float* alphD = (float*)p;  p += (size_t)NND * NH * 4;
    float* accum = (float*)p;  p += (size_t)NND * HID * 4;
    float* bnst  = (float*)p;  p += 8 * 256 * 4;
    float* va2   = (float*)p;  p += 1024 * 4;
    unsigned short* W1f = (unsigned short*)p; p += 16384 * 2;
    unsigned short* W2f = (unsigned short*)p; p += 32768 * 2;
    unsigned short* Wsf = (unsigned short*)p; p += 32768 * 2;
    unsigned short* Wsl = (unsigned short*)p; p += 32768 * 2;
    unsigned short* pWh = (unsigned short*)p; p += 8192 * 2;
    unsigned short* pWl = (unsigned short*)p; p += 8192 * 2;
    int*   deg   = (int*)p;    p += (size_t)NND * 4;
    int*   cur   = (int*)p;    p += (size_t)NND * 4;
    int*   off   = (int*)p;    p += (size_t)(NND + 1) * 4 + 4;
    int*   srcs  = (int*)p;    p += (size_t)ETOT * 4;
    int*   edst  = (int*)p;    p += (size_t)ETOT * 4;
    ushort4* ewb = (ushort4*)p; p += (size_t)ETOT * 8;
    int*   bsum  = (int*)p;    p += NB * 4;
    int*   bpre  = (int*)p;    p += NB * 4;

    // CSR build (graph constant across layers) + weight packing + va (both layers)
    k_zero_deg<<<NB, 256, 0, stream>>>(deg);
    k_count<<<(ETOT + 255) / 256, 256, 0, stream>>>(eidx, deg);
    k_bsum<<<NB, 256, 0, stream>>>(deg, bsum);
    k_bscan<<<1, 256, 0, stream>>>(bsum, bpre, off);
    k_offsets<<<NB, 256, 0, stream>>>(deg, bpre, off, cur);
    k_fill<<<(ETOT + 255) / 256, 256, 0, stream>>>(eidx, cur, srcs, edst);
    k_packw<<<192, 256, 0, stream>>>(W1, W2, gatW, pW, W1f, W2f, Wsf, Wsl, pWh, pWl);
    k_va2<<<2, 512, 0, stream>>>(gatW, attS, attD, va2);

    k_feat_mfma<<<512, 256, 0, stream>>>(x_cat, x_num, x_coord, emb, fB, pWh, pWl, pb,
                                         x, xbf);
    k_alpha2<<<2048, 256, 0, stream>>>(xbf, va2, alphS, alphD);
    for (int l = 0; l < 2; ++l) {
        k_edge_w<<<(ETOT + 255) / 256, 256, 0, stream>>>(srcs, edst, alphS, alphD,
                                                         ewb, bnst);
        k_agg_trans<<<1024, 256, 0, stream>>>(off, srcs, ewb, xbf,
                                              Wsf + (size_t)l * 16384,
                                              Wsl + (size_t)l * 16384,
                                              gatB + l * HID, accum, bnst);
        k_bn_alpha<<<2048, 256, 0, stream>>>(accum, bnst, bnG + l * HID, bnB + l * HID,
                                             x, xbf, va2 + 512, alphS, alphD,
                                             l == 0 ? 1 : 0);
    }
    k_mlp_mfma<<<256, 256, 0, stream>>>(xbf, W1f, W2f, b1, b2, W3, b3, out);
}